// Round 1
// baseline (6813.881 us; speedup 1.0000x reference)
//
#include <hip/hip_runtime.h>
#include <math.h>

#define NN 50000
#define NE 600000
#define C 128
#define H 8
#define LN_EPS 1e-5f

__device__ __forceinline__ float clip5(float x){ return fminf(fmaxf(x, -5.f), 5.f); }

// sum across a 32-lane group (lanes [0..31] or [32..63] of the wave64)
__device__ __forceinline__ float red32(float v){
  v += __shfl_xor(v, 1);  v += __shfl_xor(v, 2);  v += __shfl_xor(v, 4);
  v += __shfl_xor(v, 8);  v += __shfl_xor(v, 16);
  return v;
}

// ---------------------------------------------------------------------------
// Kernel 1: node LN1 + fused QKV projection.  8 nodes / 256-thread block.
// thread: slot=tid>>5 (node), tg=tid&31, owns cols c0..c0+3.
// ---------------------------------------------------------------------------
__global__ void __launch_bounds__(256)
k_node_ln_qkv(const float* __restrict__ nf,
              const float* __restrict__ Wq, const float* __restrict__ Wk,
              const float* __restrict__ Wv,
              const float* __restrict__ g, const float* __restrict__ b,
              float* __restrict__ qb, float* __restrict__ kb, float* __restrict__ vb)
{
  __shared__ __align__(16) float s_h[8][C];
  const int tid = threadIdx.x;
  const int slot = tid >> 5, tg = tid & 31, c0 = tg * 4;
  const int node = blockIdx.x * 8 + slot;
  const bool valid = node < NN;
  const size_t nn = valid ? (size_t)node : 0;

  const float4 x = *(const float4*)(nf + nn * C + c0);
  float s  = x.x + x.y + x.z + x.w;
  float sq = x.x*x.x + x.y*x.y + x.z*x.z + x.w*x.w;
  s = red32(s); sq = red32(sq);
  const float mu   = s * (1.0f / C);
  const float rstd = rsqrtf(sq * (1.0f / C) - mu * mu + LN_EPS);
  const float4 gg = *(const float4*)(g + c0);
  const float4 bb = *(const float4*)(b + c0);
  float4 hv;
  hv.x = (x.x - mu) * rstd * gg.x + bb.x;
  hv.y = (x.y - mu) * rstd * gg.y + bb.y;
  hv.z = (x.z - mu) * rstd * gg.z + bb.z;
  hv.w = (x.w - mu) * rstd * gg.w + bb.w;
  *(float4*)&s_h[slot][c0] = hv;
  __syncthreads();

  const float4* Wq4 = (const float4*)Wq;
  const float4* Wk4 = (const float4*)Wk;
  const float4* Wv4 = (const float4*)Wv;
  float aq0=0,aq1=0,aq2=0,aq3=0, ak0=0,ak1=0,ak2=0,ak3=0, av0=0,av1=0,av2=0,av3=0;
  #pragma unroll 8
  for (int k = 0; k < C; ++k){
    const float h = s_h[slot][k];
    const float4 wq = Wq4[k*32 + tg];
    const float4 wk = Wk4[k*32 + tg];
    const float4 wv = Wv4[k*32 + tg];
    aq0 += h*wq.x; aq1 += h*wq.y; aq2 += h*wq.z; aq3 += h*wq.w;
    ak0 += h*wk.x; ak1 += h*wk.y; ak2 += h*wk.z; ak3 += h*wk.w;
    av0 += h*wv.x; av1 += h*wv.y; av2 += h*wv.z; av3 += h*wv.w;
  }
  if (valid){
    float4 o;
    o.x=aq0; o.y=aq1; o.z=aq2; o.w=aq3; *(float4*)(qb + nn*C + c0) = o;
    o.x=ak0; o.y=ak1; o.z=ak2; o.w=ak3; *(float4*)(kb + nn*C + c0) = o;
    o.x=av0; o.y=av1; o.z=av2; o.w=av3; *(float4*)(vb + nn*C + c0) = o;
  }
}

// ---------------------------------------------------------------------------
// Zero-fill (ws is poisoned 0xAA before every timed call)
// ---------------------------------------------------------------------------
__global__ void k_zero(float* __restrict__ p, size_t n){
  size_t i = (size_t)blockIdx.x * blockDim.x + threadIdx.x;
  const size_t st = (size_t)gridDim.x * blockDim.x;
  for (; i < n; i += st) p[i] = 0.f;
}

// ---------------------------------------------------------------------------
// Kernel 3: fused edge pipeline.
// LN1(e) -> dist -> ep=concat(e,dist)@We -> alpha -> alphax(exp) ->
// atomic scatter (wV,z) -> e_attn@Wo_e + residual -> LN2.
// Writes e2 -> d_out edge region, en -> ws.
// We (66KB) + Wo_e (64KB) staged in LDS.  8 edges / pass, grid-stride.
// ---------------------------------------------------------------------------
__global__ void __launch_bounds__(256)
k_edge(const float* __restrict__ ef_g, const float* __restrict__ coords,
       const int*   __restrict__ eidx,
       const float* __restrict__ qb, const float* __restrict__ kb,
       const float* __restrict__ vb,
       const float* __restrict__ We, const float* __restrict__ Woe,
       const float* __restrict__ boe,
       const float* __restrict__ g1, const float* __restrict__ b1,
       const float* __restrict__ g2, const float* __restrict__ b2,
       float* __restrict__ wV, float* __restrict__ zz,
       float* __restrict__ e2_out, float* __restrict__ en_out)
{
  __shared__ __align__(16) float sWe [129*128];   // 66048 B
  __shared__ __align__(16) float sWoe[128*128];   // 65536 B
  __shared__ __align__(16) float s_e[8][C];
  __shared__ __align__(16) float s_a[8][C];
  __shared__ float sDist[8];

  const int tid = threadIdx.x;
  { // stage weights
    const float4* a = (const float4*)We;  float4* sa = (float4*)sWe;
    for (int i = tid; i < 129*32; i += 256) sa[i] = a[i];
    const float4* bsrc = (const float4*)Woe; float4* sb = (float4*)sWoe;
    for (int i = tid; i < 128*32; i += 256) sb[i] = bsrc[i];
  }
  __syncthreads();

  const int slot = tid >> 5, tg = tid & 31, c0 = tg * 4;
  const float4* sWe4 = (const float4*)sWe;
  const float4* sWo4 = (const float4*)sWoe;

  for (int e0 = blockIdx.x * 8; e0 < NE; e0 += gridDim.x * 8){
    const int edge = e0 + slot;
    const bool valid = edge < NE;
    const size_t ee = valid ? (size_t)edge : 0;
    const int row = eidx[ee];
    const int col = eidx[NE + ee];

    // ---- LN1 on edge features (x kept = original for the residual) ----
    const float4 x = *(const float4*)(ef_g + ee * C + c0);
    float s  = x.x + x.y + x.z + x.w;
    float sq = x.x*x.x + x.y*x.y + x.z*x.z + x.w*x.w;
    s = red32(s); sq = red32(sq);
    const float mu   = s * (1.0f / C);
    const float rstd = rsqrtf(sq * (1.0f / C) - mu * mu + LN_EPS);
    {
      const float4 gg = *(const float4*)(g1 + c0);
      const float4 bb = *(const float4*)(b1 + c0);
      float4 ev;
      ev.x = (x.x - mu)*rstd*gg.x + bb.x;
      ev.y = (x.y - mu)*rstd*gg.y + bb.y;
      ev.z = (x.z - mu)*rstd*gg.z + bb.z;
      ev.w = (x.w - mu)*rstd*gg.w + bb.w;
      *(float4*)&s_e[slot][c0] = ev;
    }
    if (tg == 0){
      const size_t r3 = (size_t)row * 3, c3 = (size_t)col * 3;
      const float dx = coords[r3+0] - coords[c3+0];
      const float dy = coords[r3+1] - coords[c3+1];
      const float dz = coords[r3+2] - coords[c3+2];
      sDist[slot] = 0.1f * sqrtf(dx*dx + dy*dy + dz*dz);
    }
    __syncthreads();

    // ---- ep = concat(e,dist) @ We ----
    const float dist = sDist[slot];
    float p0 = dist * sWe[16384 + c0 + 0];
    float p1 = dist * sWe[16384 + c0 + 1];
    float p2 = dist * sWe[16384 + c0 + 2];
    float p3 = dist * sWe[16384 + c0 + 3];
    #pragma unroll 8
    for (int k = 0; k < C; ++k){
      const float ev = s_e[slot][k];
      const float4 w = sWe4[k*32 + tg];
      p0 += ev*w.x; p1 += ev*w.y; p2 += ev*w.z; p3 += ev*w.w;
    }

    // ---- alpha = clip(k[row]*q[col]/4) * ep ----
    const float4 kr = *(const float4*)(kb + (size_t)row * C + c0);
    const float4 qc = *(const float4*)(qb + (size_t)col * C + c0);
    const float4 vr = *(const float4*)(vb + (size_t)row * C + c0);
    float a0 = clip5(kr.x * qc.x * 0.25f) * p0;
    float a1 = clip5(kr.y * qc.y * 0.25f) * p1;
    float a2 = clip5(kr.z * qc.z * 0.25f) * p2;
    float a3 = clip5(kr.w * qc.w * 0.25f) * p3;
    { float4 av; av.x=a0; av.y=a1; av.z=a2; av.w=a3; *(float4*)&s_a[slot][c0] = av; }

    // ---- per-head sum -> alphax ----
    float hs = a0 + a1 + a2 + a3;
    hs += __shfl_xor(hs, 1);
    hs += __shfl_xor(hs, 2);            // sum over the head's 16 channels
    const float ax = expf(clip5(hs));

    // ---- scatter to node accumulators ----
    if (valid){
      atomicAdd(&wV[(size_t)col * C + c0 + 0], vr.x * ax);
      atomicAdd(&wV[(size_t)col * C + c0 + 1], vr.y * ax);
      atomicAdd(&wV[(size_t)col * C + c0 + 2], vr.z * ax);
      atomicAdd(&wV[(size_t)col * C + c0 + 3], vr.w * ax);
      if ((tg & 3) == 0) atomicAdd(&zz[(size_t)col * H + (c0 >> 4)], ax);
    }
    __syncthreads();

    // ---- e2 = edge_feats + alpha @ Wo_e + bo_e ----
    const float4 bo = *(const float4*)(boe + c0);
    float o0 = x.x + bo.x, o1 = x.y + bo.y, o2 = x.z + bo.z, o3 = x.w + bo.w;
    #pragma unroll 8
    for (int k = 0; k < C; ++k){
      const float av = s_a[slot][k];
      const float4 w = sWo4[k*32 + tg];
      o0 += av*w.x; o1 += av*w.y; o2 += av*w.z; o3 += av*w.w;
    }

    // ---- LN2 -> en ----
    float s2  = o0 + o1 + o2 + o3;
    float sq2 = o0*o0 + o1*o1 + o2*o2 + o3*o3;
    s2 = red32(s2); sq2 = red32(sq2);
    const float mu2   = s2 * (1.0f / C);
    const float rstd2 = rsqrtf(sq2 * (1.0f / C) - mu2 * mu2 + LN_EPS);
    if (valid){
      float4 o; o.x=o0; o.y=o1; o.z=o2; o.w=o3;
      *(float4*)(e2_out + (size_t)edge * C + c0) = o;
      const float4 gg = *(const float4*)(g2 + c0);
      const float4 bb = *(const float4*)(b2 + c0);
      float4 en;
      en.x = (o0 - mu2)*rstd2*gg.x + bb.x;
      en.y = (o1 - mu2)*rstd2*gg.y + bb.y;
      en.z = (o2 - mu2)*rstd2*gg.z + bb.z;
      en.w = (o3 - mu2)*rstd2*gg.w + bb.w;
      *(float4*)(en_out + (size_t)edge * C + c0) = en;
    }
    __syncthreads();
  }
}

// ---------------------------------------------------------------------------
// Kernel 4: h_attn = wV/(z+1e-6); h2 = nf + h_attn@Wo_n + bo_n; LN2 -> hn.
// ---------------------------------------------------------------------------
__global__ void __launch_bounds__(256)
k_node_final(const float* __restrict__ nf, const float* __restrict__ wV,
             const float* __restrict__ zz,
             const float* __restrict__ Won, const float* __restrict__ bon,
             const float* __restrict__ g2, const float* __restrict__ b2,
             float* __restrict__ h2_out, float* __restrict__ hn_out)
{
  __shared__ __align__(16) float sW[128*128];
  __shared__ __align__(16) float s_h[8][C];
  const int tid = threadIdx.x;
  {
    const float4* a = (const float4*)Won; float4* sa = (float4*)sW;
    for (int i = tid; i < 128*32; i += 256) sa[i] = a[i];
  }
  __syncthreads();
  const int slot = tid >> 5, tg = tid & 31, c0 = tg * 4;
  const float4* sW4 = (const float4*)sW;

  for (int n0 = blockIdx.x * 8; n0 < NN; n0 += gridDim.x * 8){
    const int node = n0 + slot;
    const bool valid = node < NN;
    const size_t nn = valid ? (size_t)node : 0;

    const float4 wv = *(const float4*)(wV + nn * C + c0);
    const float  zh = zz[nn * H + (c0 >> 4)] + 1e-6f;
    {
      float4 ha;
      ha.x = wv.x / zh; ha.y = wv.y / zh; ha.z = wv.z / zh; ha.w = wv.w / zh;
      *(float4*)&s_h[slot][c0] = ha;
    }
    __syncthreads();

    const float4 x  = *(const float4*)(nf + nn * C + c0);
    const float4 bo = *(const float4*)(bon + c0);
    float o0 = x.x + bo.x, o1 = x.y + bo.y, o2 = x.z + bo.z, o3 = x.w + bo.w;
    #pragma unroll 8
    for (int k = 0; k < C; ++k){
      const float hv = s_h[slot][k];
      const float4 w = sW4[k*32 + tg];
      o0 += hv*w.x; o1 += hv*w.y; o2 += hv*w.z; o3 += hv*w.w;
    }

    float s2  = o0 + o1 + o2 + o3;
    float sq2 = o0*o0 + o1*o1 + o2*o2 + o3*o3;
    s2 = red32(s2); sq2 = red32(sq2);
    const float mu2   = s2 * (1.0f / C);
    const float rstd2 = rsqrtf(sq2 * (1.0f / C) - mu2 * mu2 + LN_EPS);
    if (valid){
      float4 o; o.x=o0; o.y=o1; o.z=o2; o.w=o3;
      *(float4*)(h2_out + (size_t)node * C + c0) = o;
      const float4 gg = *(const float4*)(g2 + c0);
      const float4 bb = *(const float4*)(b2 + c0);
      float4 hn;
      hn.x = (o0 - mu2)*rstd2*gg.x + bb.x;
      hn.y = (o1 - mu2)*rstd2*gg.y + bb.y;
      hn.z = (o2 - mu2)*rstd2*gg.z + bb.z;
      hn.w = (o3 - mu2)*rstd2*gg.w + bb.w;
      *(float4*)(hn_out + (size_t)node * C + c0) = hn;
    }
    __syncthreads();
  }
}

// ---------------------------------------------------------------------------
// Kernel 5: out += silu(xn @ W1) @ W2.   W1 (128KB) in LDS, W2 via L2.
// 8 rows / pass; stage1: thread owns 8 of 256 mids; stage2: 4 of 128 outs.
// ---------------------------------------------------------------------------
__global__ void __launch_bounds__(256)
k_ffn(int M, const float* __restrict__ xn, const float* __restrict__ W1,
      const float* __restrict__ W2, float* __restrict__ out)
{
  __shared__ __align__(16) float sW1[128*256];     // 128 KB
  __shared__ __align__(16) float s_x[8][C];
  __shared__ __align__(16) float s_t[8][256];
  const int tid = threadIdx.x;
  {
    const float4* a = (const float4*)W1; float4* sa = (float4*)sW1;
    for (int i = tid; i < 128*64; i += 256) sa[i] = a[i];
  }
  __syncthreads();
  const int slot = tid >> 5, tg = tid & 31, c0 = tg * 4;
  const float4* sW14 = (const float4*)sW1;
  const float4* W24  = (const float4*)W2;

  for (int r0 = blockIdx.x * 8; r0 < M; r0 += gridDim.x * 8){
    const int row = r0 + slot;
    const bool valid = row < M;
    const size_t rr = valid ? (size_t)row : 0;

    *(float4*)&s_x[slot][c0] = *(const float4*)(xn + rr * C + c0);
    __syncthreads();

    float a0=0,a1=0,a2=0,a3=0,a4=0,a5=0,a6=0,a7=0;
    #pragma unroll 4
    for (int k = 0; k < 128; ++k){
      const float xv = s_x[slot][k];
      const float4 wa = sW14[k*64 + tg*2 + 0];
      const float4 wb = sW14[k*64 + tg*2 + 1];
      a0 += xv*wa.x; a1 += xv*wa.y; a2 += xv*wa.z; a3 += xv*wa.w;
      a4 += xv*wb.x; a5 += xv*wb.y; a6 += xv*wb.z; a7 += xv*wb.w;
    }
    {
      float t[8] = {a0,a1,a2,a3,a4,a5,a6,a7};
      #pragma unroll
      for (int i = 0; i < 8; ++i){
        const float v = t[i];
        s_t[slot][tg*8 + i] = v / (1.f + expf(-v));   // silu
      }
    }
    __syncthreads();

    float o0=0,o1=0,o2=0,o3=0;
    #pragma unroll 8
    for (int k = 0; k < 256; ++k){
      const float tv = s_t[slot][k];
      const float4 w = W24[k*32 + tg];
      o0 += tv*w.x; o1 += tv*w.y; o2 += tv*w.z; o3 += tv*w.w;
    }
    if (valid){
      float4 cur = *(float4*)(out + rr * C + c0);
      cur.x += o0; cur.y += o1; cur.z += o2; cur.w += o3;
      *(float4*)(out + rr * C + c0) = cur;
    }
    __syncthreads();
  }
}

// ---------------------------------------------------------------------------
extern "C" void kernel_launch(void* const* d_in, const int* in_sizes, int n_in,
                              void* d_out, int out_size, void* d_ws, size_t ws_size,
                              hipStream_t stream)
{
  const float* nf     = (const float*)d_in[0];
  const float* ef     = (const float*)d_in[1];
  const float* coords = (const float*)d_in[2];
  const int*   eidx   = (const int*)  d_in[3];
  const float* Wq     = (const float*)d_in[4];
  const float* Wk     = (const float*)d_in[5];
  const float* Wv     = (const float*)d_in[6];
  const float* We     = (const float*)d_in[7];
  const float* Won    = (const float*)d_in[8];
  const float* bon    = (const float*)d_in[9];
  const float* Woe    = (const float*)d_in[10];
  const float* boe    = (const float*)d_in[11];
  const float* ln1ng  = (const float*)d_in[12];
  const float* ln1nb  = (const float*)d_in[13];
  const float* ln1eg  = (const float*)d_in[14];
  const float* ln1eb  = (const float*)d_in[15];
  const float* ln2ng  = (const float*)d_in[16];
  const float* ln2nb  = (const float*)d_in[17];
  const float* ln2eg  = (const float*)d_in[18];
  const float* ln2eb  = (const float*)d_in[19];
  const float* Wn1    = (const float*)d_in[20];
  const float* Wn2    = (const float*)d_in[21];
  const float* We1    = (const float*)d_in[22];
  const float* We2    = (const float*)d_in[23];

  float* out_h = (float*)d_out;
  float* out_e = out_h + (size_t)NN * C;

  float* ws = (float*)d_ws;
  float* qb = ws;
  float* kb = qb + (size_t)NN * C;
  float* vb = kb + (size_t)NN * C;
  float* wV = vb + (size_t)NN * C;
  float* zz = wV + (size_t)NN * C;     // [NN, H], contiguous after wV
  float* hn = zz + (size_t)NN * H;
  float* en = hn + (size_t)NN * C;     // [NE, C]

  hipLaunchKernelGGL(k_node_ln_qkv, dim3((NN + 7) / 8), dim3(256), 0, stream,
                     nf, Wq, Wk, Wv, ln1ng, ln1nb, qb, kb, vb);
  hipLaunchKernelGGL(k_zero, dim3(1024), dim3(256), 0, stream,
                     wV, (size_t)NN * C + (size_t)NN * H);
  hipLaunchKernelGGL(k_edge, dim3(1024), dim3(256), 0, stream,
                     ef, coords, eidx, qb, kb, vb, We, Woe, boe,
                     ln1eg, ln1eb, ln2eg, ln2eb, wV, zz, out_e, en);
  hipLaunchKernelGGL(k_node_final, dim3(1024), dim3(256), 0, stream,
                     nf, wV, zz, Won, bon, ln2ng, ln2nb, out_h, hn);
  hipLaunchKernelGGL(k_ffn, dim3(1024), dim3(256), 0, stream,
                     NN, hn, Wn1, Wn2, out_h);
  hipLaunchKernelGGL(k_ffn, dim3(2048), dim3(256), 0, stream,
                     NE, en, We1, We2, out_e);
}

// Round 2
// 3751.577 us; speedup vs baseline: 1.8163x; 1.8163x over previous
//
#include <hip/hip_runtime.h>
#include <math.h>

#define NN 50000
#define NE 600000
#define C 128
#define H 8
#define LN_EPS 1e-5f

typedef __attribute__((ext_vector_type(8))) short bf16x8;
typedef __attribute__((ext_vector_type(4))) float f32x4;
#define MFMA16 __builtin_amdgcn_mfma_f32_16x16x32_bf16

__device__ __forceinline__ float clip5(float x){ return fminf(fmaxf(x, -5.f), 5.f); }

__device__ __forceinline__ float red32(float v){
  v += __shfl_xor(v, 1);  v += __shfl_xor(v, 2);  v += __shfl_xor(v, 4);
  v += __shfl_xor(v, 8);  v += __shfl_xor(v, 16);
  return v;
}

// manual RNE float->bf16 (bits) and back
__device__ __forceinline__ unsigned short f2bf(float f){
  union { float f; unsigned u; } c; c.f = f;
  unsigned r = (c.u + 0x7fffu + ((c.u >> 16) & 1u)) >> 16;
  return (unsigned short)r;
}
__device__ __forceinline__ float bf2f(unsigned short u){
  union { unsigned u; float f; } c; c.u = ((unsigned)u) << 16;
  return c.f;
}

__device__ __forceinline__ bf16x8 ld_frag(const unsigned short* p){
  return *(const bf16x8*)p;
}

// ---------------------------------------------------------------------------
// Kernel 1: node LN1 + fused QKV projection.  8 nodes / 256-thread block.
// ---------------------------------------------------------------------------
__global__ void __launch_bounds__(256)
k_node_ln_qkv(const float* __restrict__ nf,
              const float* __restrict__ Wq, const float* __restrict__ Wk,
              const float* __restrict__ Wv,
              const float* __restrict__ g, const float* __restrict__ b,
              float* __restrict__ qb, float* __restrict__ kb, float* __restrict__ vb)
{
  __shared__ __align__(16) float s_h[8][C];
  const int tid = threadIdx.x;
  const int slot = tid >> 5, tg = tid & 31, c0 = tg * 4;
  const int node = blockIdx.x * 8 + slot;
  const bool valid = node < NN;
  const size_t nn = valid ? (size_t)node : 0;

  const float4 x = *(const float4*)(nf + nn * C + c0);
  float s  = x.x + x.y + x.z + x.w;
  float sq = x.x*x.x + x.y*x.y + x.z*x.z + x.w*x.w;
  s = red32(s); sq = red32(sq);
  const float mu   = s * (1.0f / C);
  const float rstd = rsqrtf(sq * (1.0f / C) - mu * mu + LN_EPS);
  const float4 gg = *(const float4*)(g + c0);
  const float4 bb = *(const float4*)(b + c0);
  float4 hv;
  hv.x = (x.x - mu) * rstd * gg.x + bb.x;
  hv.y = (x.y - mu) * rstd * gg.y + bb.y;
  hv.z = (x.z - mu) * rstd * gg.z + bb.z;
  hv.w = (x.w - mu) * rstd * gg.w + bb.w;
  *(float4*)&s_h[slot][c0] = hv;
  __syncthreads();

  const float4* Wq4 = (const float4*)Wq;
  const float4* Wk4 = (const float4*)Wk;
  const float4* Wv4 = (const float4*)Wv;
  float aq0=0,aq1=0,aq2=0,aq3=0, ak0=0,ak1=0,ak2=0,ak3=0, av0=0,av1=0,av2=0,av3=0;
  #pragma unroll 8
  for (int k = 0; k < C; ++k){
    const float h = s_h[slot][k];
    const float4 wq = Wq4[k*32 + tg];
    const float4 wk = Wk4[k*32 + tg];
    const float4 wv = Wv4[k*32 + tg];
    aq0 += h*wq.x; aq1 += h*wq.y; aq2 += h*wq.z; aq3 += h*wq.w;
    ak0 += h*wk.x; ak1 += h*wk.y; ak2 += h*wk.z; ak3 += h*wk.w;
    av0 += h*wv.x; av1 += h*wv.y; av2 += h*wv.z; av3 += h*wv.w;
  }
  if (valid){
    float4 o;
    o.x=aq0; o.y=aq1; o.z=aq2; o.w=aq3; *(float4*)(qb + nn*C + c0) = o;
    o.x=ak0; o.y=ak1; o.z=ak2; o.w=ak3; *(float4*)(kb + nn*C + c0) = o;
    o.x=av0; o.y=av1; o.z=av2; o.w=av3; *(float4*)(vb + nn*C + c0) = o;
  }
}

// ---------------------------------------------------------------------------
__global__ void k_zero(float* __restrict__ p, size_t n){
  size_t i = (size_t)blockIdx.x * blockDim.x + threadIdx.x;
  const size_t st = (size_t)gridDim.x * blockDim.x;
  for (; i < n; i += st) p[i] = 0.f;
}

// ---------------------------------------------------------------------------
// Prep: build transposed + hi/lo-split bf16 copies of the 4 FFN weights.
// out layout: 8 arrays of 32768 ushort: wn1h,wn1l,wn2h,wn2l,we1h,we1l,we2h,we2l
// For W[K][N] -> WT[N][K]; e = n*K + k.
// ---------------------------------------------------------------------------
__global__ void __launch_bounds__(256)
k_prep(const float* __restrict__ Wn1, const float* __restrict__ Wn2,
       const float* __restrict__ We1, const float* __restrict__ We2,
       unsigned short* __restrict__ o)
{
  const int id = blockIdx.x * 256 + threadIdx.x;   // 131072 total
  const int w = id >> 15, e = id & 32767;
  const float* src; int K, Nn;
  if      (w == 0){ src = Wn1; K = 128; Nn = 256; }
  else if (w == 1){ src = Wn2; K = 256; Nn = 128; }
  else if (w == 2){ src = We1; K = 128; Nn = 256; }
  else            { src = We2; K = 256; Nn = 128; }
  const int n = (K == 128) ? (e >> 7) : (e >> 8);
  const int k = e - n * K;
  const float v = src[(size_t)k * Nn + n];
  const unsigned short h = f2bf(v);
  const unsigned short l = f2bf(v - bf2f(h));
  unsigned short* oh = o + (size_t)w * 65536;
  oh[e] = h;
  oh[32768 + e] = l;
}

// ---------------------------------------------------------------------------
// Kernel 3: fused edge pipeline (unchanged math); epilogue now emits en as
// bf16 hi/lo pair for the MFMA FFN.
// ---------------------------------------------------------------------------
__global__ void __launch_bounds__(256)
k_edge(const float* __restrict__ ef_g, const float* __restrict__ coords,
       const int*   __restrict__ eidx,
       const float* __restrict__ qb, const float* __restrict__ kb,
       const float* __restrict__ vb,
       const float* __restrict__ We, const float* __restrict__ Woe,
       const float* __restrict__ boe,
       const float* __restrict__ g1, const float* __restrict__ b1,
       const float* __restrict__ g2, const float* __restrict__ b2,
       float* __restrict__ wV, float* __restrict__ zz,
       float* __restrict__ e2_out,
       unsigned short* __restrict__ enh, unsigned short* __restrict__ enl)
{
  __shared__ __align__(16) float sWe [129*128];
  __shared__ __align__(16) float sWoe[128*128];
  __shared__ __align__(16) float s_e[8][C];
  __shared__ __align__(16) float s_a[8][C];
  __shared__ float sDist[8];

  const int tid = threadIdx.x;
  {
    const float4* a = (const float4*)We;  float4* sa = (float4*)sWe;
    for (int i = tid; i < 129*32; i += 256) sa[i] = a[i];
    const float4* bsrc = (const float4*)Woe; float4* sb = (float4*)sWoe;
    for (int i = tid; i < 128*32; i += 256) sb[i] = bsrc[i];
  }
  __syncthreads();

  const int slot = tid >> 5, tg = tid & 31, c0 = tg * 4;
  const float4* sWe4 = (const float4*)sWe;
  const float4* sWo4 = (const float4*)sWoe;

  for (int e0 = blockIdx.x * 8; e0 < NE; e0 += gridDim.x * 8){
    const int edge = e0 + slot;
    const bool valid = edge < NE;
    const size_t ee = valid ? (size_t)edge : 0;
    const int row = eidx[ee];
    const int col = eidx[NE + ee];

    const float4 x = *(const float4*)(ef_g + ee * C + c0);
    float s  = x.x + x.y + x.z + x.w;
    float sq = x.x*x.x + x.y*x.y + x.z*x.z + x.w*x.w;
    s = red32(s); sq = red32(sq);
    const float mu   = s * (1.0f / C);
    const float rstd = rsqrtf(sq * (1.0f / C) - mu * mu + LN_EPS);
    {
      const float4 gg = *(const float4*)(g1 + c0);
      const float4 bb = *(const float4*)(b1 + c0);
      float4 ev;
      ev.x = (x.x - mu)*rstd*gg.x + bb.x;
      ev.y = (x.y - mu)*rstd*gg.y + bb.y;
      ev.z = (x.z - mu)*rstd*gg.z + bb.z;
      ev.w = (x.w - mu)*rstd*gg.w + bb.w;
      *(float4*)&s_e[slot][c0] = ev;
    }
    if (tg == 0){
      const size_t r3 = (size_t)row * 3, c3 = (size_t)col * 3;
      const float dx = coords[r3+0] - coords[c3+0];
      const float dy = coords[r3+1] - coords[c3+1];
      const float dz = coords[r3+2] - coords[c3+2];
      sDist[slot] = 0.1f * sqrtf(dx*dx + dy*dy + dz*dz);
    }
    __syncthreads();

    const float dist = sDist[slot];
    float p0 = dist * sWe[16384 + c0 + 0];
    float p1 = dist * sWe[16384 + c0 + 1];
    float p2 = dist * sWe[16384 + c0 + 2];
    float p3 = dist * sWe[16384 + c0 + 3];
    #pragma unroll 8
    for (int k = 0; k < C; ++k){
      const float ev = s_e[slot][k];
      const float4 w = sWe4[k*32 + tg];
      p0 += ev*w.x; p1 += ev*w.y; p2 += ev*w.z; p3 += ev*w.w;
    }

    const float4 kr = *(const float4*)(kb + (size_t)row * C + c0);
    const float4 qc = *(const float4*)(qb + (size_t)col * C + c0);
    const float4 vr = *(const float4*)(vb + (size_t)row * C + c0);
    float a0 = clip5(kr.x * qc.x * 0.25f) * p0;
    float a1 = clip5(kr.y * qc.y * 0.25f) * p1;
    float a2 = clip5(kr.z * qc.z * 0.25f) * p2;
    float a3 = clip5(kr.w * qc.w * 0.25f) * p3;
    { float4 av; av.x=a0; av.y=a1; av.z=a2; av.w=a3; *(float4*)&s_a[slot][c0] = av; }

    float hs = a0 + a1 + a2 + a3;
    hs += __shfl_xor(hs, 1);
    hs += __shfl_xor(hs, 2);
    const float ax = expf(clip5(hs));

    if (valid){
      atomicAdd(&wV[(size_t)col * C + c0 + 0], vr.x * ax);
      atomicAdd(&wV[(size_t)col * C + c0 + 1], vr.y * ax);
      atomicAdd(&wV[(size_t)col * C + c0 + 2], vr.z * ax);
      atomicAdd(&wV[(size_t)col * C + c0 + 3], vr.w * ax);
      if ((tg & 3) == 0) atomicAdd(&zz[(size_t)col * H + (c0 >> 4)], ax);
    }
    __syncthreads();

    const float4 bo = *(const float4*)(boe + c0);
    float o0 = x.x + bo.x, o1 = x.y + bo.y, o2 = x.z + bo.z, o3 = x.w + bo.w;
    #pragma unroll 8
    for (int k = 0; k < C; ++k){
      const float av = s_a[slot][k];
      const float4 w = sWo4[k*32 + tg];
      o0 += av*w.x; o1 += av*w.y; o2 += av*w.z; o3 += av*w.w;
    }

    float s2  = o0 + o1 + o2 + o3;
    float sq2 = o0*o0 + o1*o1 + o2*o2 + o3*o3;
    s2 = red32(s2); sq2 = red32(sq2);
    const float mu2   = s2 * (1.0f / C);
    const float rstd2 = rsqrtf(sq2 * (1.0f / C) - mu2 * mu2 + LN_EPS);
    if (valid){
      float4 o; o.x=o0; o.y=o1; o.z=o2; o.w=o3;
      *(float4*)(e2_out + (size_t)edge * C + c0) = o;
      const float4 gg = *(const float4*)(g2 + c0);
      const float4 bb = *(const float4*)(b2 + c0);
      float e0v = (o0 - mu2)*rstd2*gg.x + bb.x;
      float e1v = (o1 - mu2)*rstd2*gg.y + bb.y;
      float e2v = (o2 - mu2)*rstd2*gg.z + bb.z;
      float e3v = (o3 - mu2)*rstd2*gg.w + bb.w;
      ushort4 hh, ll;
      hh.x = f2bf(e0v); ll.x = f2bf(e0v - bf2f(hh.x));
      hh.y = f2bf(e1v); ll.y = f2bf(e1v - bf2f(hh.y));
      hh.z = f2bf(e2v); ll.z = f2bf(e2v - bf2f(hh.z));
      hh.w = f2bf(e3v); ll.w = f2bf(e3v - bf2f(hh.w));
      *(ushort4*)(enh + (size_t)edge * C + c0) = hh;
      *(ushort4*)(enl + (size_t)edge * C + c0) = ll;
    }
    __syncthreads();
  }
}

// ---------------------------------------------------------------------------
// Kernel 4: node attention epilogue; emits hn as bf16 hi/lo.
// ---------------------------------------------------------------------------
__global__ void __launch_bounds__(256)
k_node_final(const float* __restrict__ nf, const float* __restrict__ wV,
             const float* __restrict__ zz,
             const float* __restrict__ Won, const float* __restrict__ bon,
             const float* __restrict__ g2, const float* __restrict__ b2,
             float* __restrict__ h2_out,
             unsigned short* __restrict__ hnh, unsigned short* __restrict__ hnl)
{
  __shared__ __align__(16) float sW[128*128];
  __shared__ __align__(16) float s_h[8][C];
  const int tid = threadIdx.x;
  {
    const float4* a = (const float4*)Won; float4* sa = (float4*)sW;
    for (int i = tid; i < 128*32; i += 256) sa[i] = a[i];
  }
  __syncthreads();
  const int slot = tid >> 5, tg = tid & 31, c0 = tg * 4;
  const float4* sW4 = (const float4*)sW;

  for (int n0 = blockIdx.x * 8; n0 < NN; n0 += gridDim.x * 8){
    const int node = n0 + slot;
    const bool valid = node < NN;
    const size_t nn = valid ? (size_t)node : 0;

    const float4 wv = *(const float4*)(wV + nn * C + c0);
    const float  zh = zz[nn * H + (c0 >> 4)] + 1e-6f;
    {
      float4 ha;
      ha.x = wv.x / zh; ha.y = wv.y / zh; ha.z = wv.z / zh; ha.w = wv.w / zh;
      *(float4*)&s_h[slot][c0] = ha;
    }
    __syncthreads();

    const float4 x  = *(const float4*)(nf + nn * C + c0);
    const float4 bo = *(const float4*)(bon + c0);
    float o0 = x.x + bo.x, o1 = x.y + bo.y, o2 = x.z + bo.z, o3 = x.w + bo.w;
    #pragma unroll 8
    for (int k = 0; k < C; ++k){
      const float hv = s_h[slot][k];
      const float4 w = sW4[k*32 + tg];
      o0 += hv*w.x; o1 += hv*w.y; o2 += hv*w.z; o3 += hv*w.w;
    }

    float s2  = o0 + o1 + o2 + o3;
    float sq2 = o0*o0 + o1*o1 + o2*o2 + o3*o3;
    s2 = red32(s2); sq2 = red32(sq2);
    const float mu2   = s2 * (1.0f / C);
    const float rstd2 = rsqrtf(sq2 * (1.0f / C) - mu2 * mu2 + LN_EPS);
    if (valid){
      float4 o; o.x=o0; o.y=o1; o.z=o2; o.w=o3;
      *(float4*)(h2_out + (size_t)node * C + c0) = o;
      const float4 gg = *(const float4*)(g2 + c0);
      const float4 bb = *(const float4*)(b2 + c0);
      float h0 = (o0 - mu2)*rstd2*gg.x + bb.x;
      float h1 = (o1 - mu2)*rstd2*gg.y + bb.y;
      float h2 = (o2 - mu2)*rstd2*gg.z + bb.z;
      float h3 = (o3 - mu2)*rstd2*gg.w + bb.w;
      ushort4 hh, ll;
      hh.x = f2bf(h0); ll.x = f2bf(h0 - bf2f(hh.x));
      hh.y = f2bf(h1); ll.y = f2bf(h1 - bf2f(hh.y));
      hh.z = f2bf(h2); ll.z = f2bf(h2 - bf2f(hh.z));
      hh.w = f2bf(h3); ll.w = f2bf(h3 - bf2f(hh.w));
      *(ushort4*)(hnh + (size_t)node * C + c0) = hh;
      *(ushort4*)(hnl + (size_t)node * C + c0) = ll;
    }
    __syncthreads();
  }
}

// ---------------------------------------------------------------------------
// Kernel 5: MFMA FFN.  out[M,128] += silu(x[M,128] @ W1[128,256]) @ W2[256,128]
// x given as bf16 hi/lo (xh,xl); weights transposed+split (w1*: [256][128],
// w2*: [128][256]).  3-term split emulation per GEMM -> ~fp32 accuracy.
// GEMM1 computed transposed (A=W1T frags, B=x frags) so D1 has x-row on
// lane&15; t redistribution to GEMM2's A-operand is a pure quad-permutation
// done with ds_bpermute.  Zero LDS.  32 rows/wave, 128 rows/block.
// ---------------------------------------------------------------------------
__global__ void __launch_bounds__(256, 2)
k_ffn_mfma(int M,
           const unsigned short* __restrict__ xh, const unsigned short* __restrict__ xl,
           const unsigned short* __restrict__ w1h, const unsigned short* __restrict__ w1l,
           const unsigned short* __restrict__ w2h, const unsigned short* __restrict__ w2l,
           float* __restrict__ out)
{
  const int tid  = threadIdx.x;
  const int wid  = tid >> 6;
  const int lane = tid & 63;
  const int r = lane & 15;
  const int q = lane >> 4;
  const int rowbase = (blockIdx.x * 4 + wid) * 32;

  // B1 frags: x rows, 2 rowsets x 4 k-steps, hi+lo
  bf16x8 bh[2][4], bl[2][4];
  #pragma unroll
  for (int s = 0; s < 2; ++s){
    int row = rowbase + s*16 + r;
    if (row > M-1) row = M-1;
    const size_t base = (size_t)row * 128 + q * 8;
    #pragma unroll
    for (int gk = 0; gk < 4; ++gk){
      bh[s][gk] = ld_frag(xh + base + gk*32);
      bl[s][gk] = ld_frag(xl + base + gk*32);
    }
  }

  f32x4 acc[2][8];
  #pragma unroll
  for (int s = 0; s < 2; ++s)
    #pragma unroll
    for (int nt = 0; nt < 8; ++nt)
      acc[s][nt] = (f32x4){0.f, 0.f, 0.f, 0.f};

  const int src0 = (r + ((lane & 16) << 1)) << 2;  // byte addr for bpermute
  const int src1 = src0 + 64;
  const bool hi = (lane >= 32);

  for (int p = 0; p < 8; ++p){
    #pragma unroll
    for (int s = 0; s < 2; ++s){
      int tw[2][4];                       // per t-tile: h.w0, h.w1, l.w0, l.w1
      #pragma unroll
      for (int t = 0; t < 2; ++t){
        const size_t abase = (size_t)((2*p + t)*16 + r) * 128 + q*8;
        f32x4 c = (f32x4){0.f, 0.f, 0.f, 0.f};
        #pragma unroll
        for (int gk = 0; gk < 4; ++gk){
          bf16x8 ah = ld_frag(w1h + abase + gk*32);
          bf16x8 al = ld_frag(w1l + abase + gk*32);
          c = MFMA16(ah, bh[s][gk], c, 0, 0, 0);
          c = MFMA16(ah, bl[s][gk], c, 0, 0, 0);
          c = MFMA16(al, bh[s][gk], c, 0, 0, 0);
        }
        unsigned short th[4], tl_[4];
        #pragma unroll
        for (int i = 0; i < 4; ++i){
          float v = c[i];
          v = v / (1.f + __expf(-v));     // silu
          th[i]  = f2bf(v);
          tl_[i] = f2bf(v - bf2f(th[i]));
        }
        tw[t][0] = (int)th[0]  | ((int)th[1]  << 16);
        tw[t][1] = (int)th[2]  | ((int)th[3]  << 16);
        tw[t][2] = (int)tl_[0] | ((int)tl_[1] << 16);
        tw[t][3] = (int)tl_[2] | ((int)tl_[3] << 16);
      }
      // redistribute t (D1' layout) -> A2 frag layout via quad permutation
      int u0, u1;
      union { int i[4]; bf16x8 v; } a2h, a2l;
      u0 = __builtin_amdgcn_ds_bpermute(src0, tw[0][0]);
      u1 = __builtin_amdgcn_ds_bpermute(src0, tw[1][0]);
      a2h.i[0] = hi ? u1 : u0;
      u0 = __builtin_amdgcn_ds_bpermute(src0, tw[0][1]);
      u1 = __builtin_amdgcn_ds_bpermute(src0, tw[1][1]);
      a2h.i[1] = hi ? u1 : u0;
      u0 = __builtin_amdgcn_ds_bpermute(src1, tw[0][0]);
      u1 = __builtin_amdgcn_ds_bpermute(src1, tw[1][0]);
      a2h.i[2] = hi ? u1 : u0;
      u0 = __builtin_amdgcn_ds_bpermute(src1, tw[0][1]);
      u1 = __builtin_amdgcn_ds_bpermute(src1, tw[1][1]);
      a2h.i[3] = hi ? u1 : u0;
      u0 = __builtin_amdgcn_ds_bpermute(src0, tw[0][2]);
      u1 = __builtin_amdgcn_ds_bpermute(src0, tw[1][2]);
      a2l.i[0] = hi ? u1 : u0;
      u0 = __builtin_amdgcn_ds_bpermute(src0, tw[0][3]);
      u1 = __builtin_amdgcn_ds_bpermute(src0, tw[1][3]);
      a2l.i[1] = hi ? u1 : u0;
      u0 = __builtin_amdgcn_ds_bpermute(src1, tw[0][2]);
      u1 = __builtin_amdgcn_ds_bpermute(src1, tw[1][2]);
      a2l.i[2] = hi ? u1 : u0;
      u0 = __builtin_amdgcn_ds_bpermute(src1, tw[0][3]);
      u1 = __builtin_amdgcn_ds_bpermute(src1, tw[1][3]);
      a2l.i[3] = hi ? u1 : u0;

      // GEMM2: acc[s][nt] += t-frags @ W2T frags
      #pragma unroll
      for (int nt = 0; nt < 8; ++nt){
        const size_t b2base = (size_t)(nt*16 + r) * 256 + p*32 + q*8;
        bf16x8 b2h = ld_frag(w2h + b2base);
        bf16x8 b2l = ld_frag(w2l + b2base);
        acc[s][nt] = MFMA16(a2h.v, b2h, acc[s][nt], 0, 0, 0);
        acc[s][nt] = MFMA16(a2l.v, b2h, acc[s][nt], 0, 0, 0);
        acc[s][nt] = MFMA16(a2h.v, b2l, acc[s][nt], 0, 0, 0);
      }
    }
  }

  // RMW store: out[row][n] += e3
  #pragma unroll
  for (int s = 0; s < 2; ++s){
    #pragma unroll
    for (int nt = 0; nt < 8; ++nt){
      #pragma unroll
      for (int i = 0; i < 4; ++i){
        const int row = rowbase + s*16 + q*4 + i;
        if (row < M){
          const size_t idx = (size_t)row * 128 + nt*16 + r;
          out[idx] += acc[s][nt][i];
        }
      }
    }
  }
}

// ---------------------------------------------------------------------------
extern "C" void kernel_launch(void* const* d_in, const int* in_sizes, int n_in,
                              void* d_out, int out_size, void* d_ws, size_t ws_size,
                              hipStream_t stream)
{
  const float* nf     = (const float*)d_in[0];
  const float* ef     = (const float*)d_in[1];
  const float* coords = (const float*)d_in[2];
  const int*   eidx   = (const int*)  d_in[3];
  const float* Wq     = (const float*)d_in[4];
  const float* Wk     = (const float*)d_in[5];
  const float* Wv     = (const float*)d_in[6];
  const float* We     = (const float*)d_in[7];
  const float* Won    = (const float*)d_in[8];
  const float* bon    = (const float*)d_in[9];
  const float* Woe    = (const float*)d_in[10];
  const float* boe    = (const float*)d_in[11];
  const float* ln1ng  = (const float*)d_in[12];
  const float* ln1nb  = (const float*)d_in[13];
  const float* ln1eg  = (const float*)d_in[14];
  const float* ln1eb  = (const float*)d_in[15];
  const float* ln2ng  = (const float*)d_in[16];
  const float* ln2nb  = (const float*)d_in[17];
  const float* ln2eg  = (const float*)d_in[18];
  const float* ln2eb  = (const float*)d_in[19];
  const float* Wn1    = (const float*)d_in[20];
  const float* Wn2    = (const float*)d_in[21];
  const float* We1    = (const float*)d_in[22];
  const float* We2    = (const float*)d_in[23];

  float* out_h = (float*)d_out;
  float* out_e = out_h + (size_t)NN * C;

  float* ws = (float*)d_ws;
  float* qb = ws;
  float* kb = qb + (size_t)NN * C;
  float* vb = kb + (size_t)NN * C;
  float* wV = vb + (size_t)NN * C;
  float* zz = wV + (size_t)NN * C;            // [NN, H]
  unsigned short* hnh = (unsigned short*)(zz + (size_t)NN * H);
  unsigned short* hnl = hnh + (size_t)NN * C;
  unsigned short* enh = hnl + (size_t)NN * C;
  unsigned short* enl = enh + (size_t)NE * C;
  unsigned short* wts = enl + (size_t)NE * C; // 8 x 32768
  unsigned short* wn1h = wts + 0*32768;
  unsigned short* wn1l = wts + 1*32768;
  unsigned short* wn2h = wts + 2*32768;
  unsigned short* wn2l = wts + 3*32768;
  unsigned short* we1h = wts + 4*32768;
  unsigned short* we1l = wts + 5*32768;
  unsigned short* we2h = wts + 6*32768;
  unsigned short* we2l = wts + 7*32768;

  hipLaunchKernelGGL(k_prep, dim3(512), dim3(256), 0, stream,
                     Wn1, Wn2, We1, We2, wts);
  hipLaunchKernelGGL(k_node_ln_qkv, dim3((NN + 7) / 8), dim3(256), 0, stream,
                     nf, Wq, Wk, Wv, ln1ng, ln1nb, qb, kb, vb);
  hipLaunchKernelGGL(k_zero, dim3(1024), dim3(256), 0, stream,
                     wV, (size_t)NN * C + (size_t)NN * H);
  hipLaunchKernelGGL(k_edge, dim3(1024), dim3(256), 0, stream,
                     ef, coords, eidx, qb, kb, vb, We, Woe, boe,
                     ln1eg, ln1eb, ln2eg, ln2eb, wV, zz, out_e, enh, enl);
  hipLaunchKernelGGL(k_node_final, dim3(1024), dim3(256), 0, stream,
                     nf, wV, zz, Won, bon, ln2ng, ln2nb, out_h, hnh, hnl);
  hipLaunchKernelGGL(k_ffn_mfma, dim3((NN + 127) / 128), dim3(256), 0, stream,
                     NN, hnh, hnl, wn1h, wn1l, wn2h, wn2l, out_h);
  hipLaunchKernelGGL(k_ffn_mfma, dim3((NE + 127) / 128), dim3(256), 0, stream,
                     NE, enh, enl, we1h, we1l, we2h, we2l, out_e);
}

// Round 8
// 3199.920 us; speedup vs baseline: 2.1294x; 1.1724x over previous
//
#include <hip/hip_runtime.h>
#include <math.h>

#define NN 50000
#define NE 600000
#define C 128
#define H 8
#define LN_EPS 1e-5f

typedef __attribute__((ext_vector_type(8))) short bf16x8;
typedef __attribute__((ext_vector_type(4))) float f32x4;
#define MFMA16 __builtin_amdgcn_mfma_f32_16x16x32_bf16

__device__ __forceinline__ float clip5(float x){ return fminf(fmaxf(x, -5.f), 5.f); }

__device__ __forceinline__ float red32(float v){
  v += __shfl_xor(v, 1);  v += __shfl_xor(v, 2);  v += __shfl_xor(v, 4);
  v += __shfl_xor(v, 8);  v += __shfl_xor(v, 16);
  return v;
}

// manual RNE float->bf16 (bits) and back
__device__ __forceinline__ unsigned short f2bf(float f){
  union { float f; unsigned u; } c; c.f = f;
  unsigned r = (c.u + 0x7fffu + ((c.u >> 16) & 1u)) >> 16;
  return (unsigned short)r;
}
__device__ __forceinline__ float bf2f(unsigned short u){
  union { unsigned u; float f; } c; c.u = ((unsigned)u) << 16;
  return c.f;
}

__device__ __forceinline__ bf16x8 ld_frag(const unsigned short* p){
  return *(const bf16x8*)p;
}

// ---------------------------------------------------------------------------
// Kernel 1: node LN1 + fused QKV projection.  8 nodes / 256-thread block.
// ---------------------------------------------------------------------------
__global__ void __launch_bounds__(256)
k_node_ln_qkv(const float* __restrict__ nf,
              const float* __restrict__ Wq, const float* __restrict__ Wk,
              const float* __restrict__ Wv,
              const float* __restrict__ g, const float* __restrict__ b,
              float* __restrict__ qb, float* __restrict__ kb, float* __restrict__ vb)
{
  __shared__ __align__(16) float s_h[8][C];
  const int tid = threadIdx.x;
  const int slot = tid >> 5, tg = tid & 31, c0 = tg * 4;
  const int node = blockIdx.x * 8 + slot;
  const bool valid = node < NN;
  const size_t nn = valid ? (size_t)node : 0;

  const float4 x = *(const float4*)(nf + nn * C + c0);
  float s  = x.x + x.y + x.z + x.w;
  float sq = x.x*x.x + x.y*x.y + x.z*x.z + x.w*x.w;
  s = red32(s); sq = red32(sq);
  const float mu   = s * (1.0f / C);
  const float rstd = rsqrtf(sq * (1.0f / C) - mu * mu + LN_EPS);
  const float4 gg = *(const float4*)(g + c0);
  const float4 bb = *(const float4*)(b + c0);
  float4 hv;
  hv.x = (x.x - mu) * rstd * gg.x + bb.x;
  hv.y = (x.y - mu) * rstd * gg.y + bb.y;
  hv.z = (x.z - mu) * rstd * gg.z + bb.z;
  hv.w = (x.w - mu) * rstd * gg.w + bb.w;
  *(float4*)&s_h[slot][c0] = hv;
  __syncthreads();

  const float4* Wq4 = (const float4*)Wq;
  const float4* Wk4 = (const float4*)Wk;
  const float4* Wv4 = (const float4*)Wv;
  float aq0=0,aq1=0,aq2=0,aq3=0, ak0=0,ak1=0,ak2=0,ak3=0, av0=0,av1=0,av2=0,av3=0;
  #pragma unroll 8
  for (int k = 0; k < C; ++k){
    const float h = s_h[slot][k];
    const float4 wq = Wq4[k*32 + tg];
    const float4 wk = Wk4[k*32 + tg];
    const float4 wv = Wv4[k*32 + tg];
    aq0 += h*wq.x; aq1 += h*wq.y; aq2 += h*wq.z; aq3 += h*wq.w;
    ak0 += h*wk.x; ak1 += h*wk.y; ak2 += h*wk.z; ak3 += h*wk.w;
    av0 += h*wv.x; av1 += h*wv.y; av2 += h*wv.z; av3 += h*wv.w;
  }
  if (valid){
    float4 o;
    o.x=aq0; o.y=aq1; o.z=aq2; o.w=aq3; *(float4*)(qb + nn*C + c0) = o;
    o.x=ak0; o.y=ak1; o.z=ak2; o.w=ak3; *(float4*)(kb + nn*C + c0) = o;
    o.x=av0; o.y=av1; o.z=av2; o.w=av3; *(float4*)(vb + nn*C + c0) = o;
  }
}

// ---------------------------------------------------------------------------
__global__ void k_zero(float* __restrict__ p, size_t n){
  size_t i = (size_t)blockIdx.x * blockDim.x + threadIdx.x;
  const size_t st = (size_t)gridDim.x * blockDim.x;
  for (; i < n; i += st) p[i] = 0.f;
}

// ---------------------------------------------------------------------------
// Prep: transposed + hi/lo-split bf16 copies of FFN weights (as before) plus
// WeT (first 128 rows of We, transposed), WoeT, and the dist row We[128] fp32.
// ---------------------------------------------------------------------------
__global__ void __launch_bounds__(256)
k_prep(const float* __restrict__ Wn1, const float* __restrict__ Wn2,
       const float* __restrict__ We1, const float* __restrict__ We2,
       const float* __restrict__ We,  const float* __restrict__ Woe,
       unsigned short* __restrict__ o,
       unsigned short* __restrict__ weTh, unsigned short* __restrict__ weTl,
       unsigned short* __restrict__ woeTh, unsigned short* __restrict__ woeTl,
       float* __restrict__ we128f)
{
  const int id = blockIdx.x * 256 + threadIdx.x;
  if (id < 131072){
    const int w = id >> 15, e = id & 32767;
    const float* src; int K, Nn;
    if      (w == 0){ src = Wn1; K = 128; Nn = 256; }
    else if (w == 1){ src = Wn2; K = 256; Nn = 128; }
    else if (w == 2){ src = We1; K = 128; Nn = 256; }
    else            { src = We2; K = 256; Nn = 128; }
    const int n = (K == 128) ? (e >> 7) : (e >> 8);
    const int k = e - n * K;
    const float v = src[(size_t)k * Nn + n];
    const unsigned short h = f2bf(v);
    const unsigned short l = f2bf(v - bf2f(h));
    unsigned short* oh = o + (size_t)w * 65536;
    oh[e] = h;
    oh[32768 + e] = l;
  } else if (id < 147456){
    const int e = id - 131072;
    const int n = e >> 7, k = e & 127;
    const float v = We[(size_t)k * 128 + n];
    const unsigned short h = f2bf(v);
    weTh[e] = h; weTl[e] = f2bf(v - bf2f(h));
  } else if (id < 163840){
    const int e = id - 147456;
    const int n = e >> 7, k = e & 127;
    const float v = Woe[(size_t)k * 128 + n];
    const unsigned short h = f2bf(v);
    woeTh[e] = h; woeTl[e] = f2bf(v - bf2f(h));
  } else if (id < 163968){
    const int c = id - 163840;
    we128f[c] = We[128 * 128 + c];
  }
}

// ---------------------------------------------------------------------------
// Kernel 3: MFMA edge pipeline.  16 edges/wave, 64 edges/block, zero LDS.
// LN1(e)->split bf16 B-frags; GEMM1 (A=WeT) -> ep with edge on lane&15;
// alpha/exp/scatter lane-local; bpermute -> GEMM2 A-frags; GEMM2 (B=WoeT);
// epilogue: residual + LN2 + e2/en(split) stores.
// ---------------------------------------------------------------------------
__global__ void __launch_bounds__(256, 2)
k_edge_mfma(const float* __restrict__ ef, const float* __restrict__ coords,
            const int* __restrict__ eidx,
            const float* __restrict__ qb, const float* __restrict__ kb,
            const float* __restrict__ vb,
            const unsigned short* __restrict__ weTh, const unsigned short* __restrict__ weTl,
            const float* __restrict__ we128,
            const unsigned short* __restrict__ woeTh, const unsigned short* __restrict__ woeTl,
            const float* __restrict__ boe,
            const float* __restrict__ g1, const float* __restrict__ b1,
            const float* __restrict__ g2, const float* __restrict__ b2,
            float* __restrict__ wV, float* __restrict__ zz,
            float* __restrict__ e2_out,
            unsigned short* __restrict__ enh, unsigned short* __restrict__ enl)
{
  const int tid  = threadIdx.x;
  const int wid  = tid >> 6;
  const int lane = tid & 63;
  const int r = lane & 15, q = lane >> 4;
  const int ebase = (blockIdx.x * 4 + wid) * 16;   // NE % 64 == 0: no tail
  const int edge  = ebase + r;
  const size_t e128 = (size_t)edge * 128;

  // ---- load ef slice + LN1 stats (reduce across q via shfl_xor 16,32) ----
  float xv[32];
  #pragma unroll
  for (int gk = 0; gk < 4; ++gk){
    const float4 a = *(const float4*)(ef + e128 + gk*32 + q*8);
    const float4 b = *(const float4*)(ef + e128 + gk*32 + q*8 + 4);
    xv[gk*8+0]=a.x; xv[gk*8+1]=a.y; xv[gk*8+2]=a.z; xv[gk*8+3]=a.w;
    xv[gk*8+4]=b.x; xv[gk*8+5]=b.y; xv[gk*8+6]=b.z; xv[gk*8+7]=b.w;
  }
  float s = 0.f, sq = 0.f;
  #pragma unroll
  for (int j = 0; j < 32; ++j){ s += xv[j]; sq += xv[j]*xv[j]; }
  s  += __shfl_xor(s, 16);  s  += __shfl_xor(s, 32);
  sq += __shfl_xor(sq, 16); sq += __shfl_xor(sq, 32);
  const float mu   = s * (1.f/128.f);
  const float rstd = rsqrtf(sq * (1.f/128.f) - mu*mu + LN_EPS);

  bf16x8 bhf[4], blf[4];
  #pragma unroll
  for (int gk = 0; gk < 4; ++gk){
    const float4 ga = *(const float4*)(g1 + gk*32 + q*8);
    const float4 gb = *(const float4*)(g1 + gk*32 + q*8 + 4);
    const float4 ba = *(const float4*)(b1 + gk*32 + q*8);
    const float4 bb = *(const float4*)(b1 + gk*32 + q*8 + 4);
    const float gv[8] = {ga.x,ga.y,ga.z,ga.w,gb.x,gb.y,gb.z,gb.w};
    const float bv[8] = {ba.x,ba.y,ba.z,ba.w,bb.x,bb.y,bb.z,bb.w};
    union { unsigned short u[8]; bf16x8 v; } ph, pl;
    #pragma unroll
    for (int j = 0; j < 8; ++j){
      const float e = (xv[gk*8+j] - mu) * rstd * gv[j] + bv[j];
      ph.u[j] = f2bf(e);
      pl.u[j] = f2bf(e - bf2f(ph.u[j]));
    }
    bhf[gk] = ph.v; blf[gk] = pl.v;
  }

  // ---- edge meta (lane-local: this lane's edge = ebase + r) ----
  const int row = eidx[edge];
  const int col = eidx[NE + edge];
  float dist;
  {
    const size_t r3 = (size_t)row*3, c3 = (size_t)col*3;
    const float dx = coords[r3+0]-coords[c3+0];
    const float dy = coords[r3+1]-coords[c3+1];
    const float dz = coords[r3+2]-coords[c3+2];
    dist = 0.1f * sqrtf(dx*dx + dy*dy + dz*dz);
  }

  const int src0 = (r + ((lane & 16) << 1)) << 2;
  const int src1 = src0 + 64;
  const bool hisel = (lane >= 32);

  f32x4 acc[8];
  #pragma unroll
  for (int nt = 0; nt < 8; ++nt) acc[nt] = (f32x4){0.f,0.f,0.f,0.f};

  #pragma unroll
  for (int w4 = 0; w4 < 4; ++w4){
    int tw[2][4];
    #pragma unroll
    for (int t = 0; t < 2; ++t){
      const int p = 2*w4 + t;
      // GEMM1 tile p: ep channels p*16+q*4+i for edge ebase+r
      f32x4 c = (f32x4){0.f,0.f,0.f,0.f};
      const size_t abase = (size_t)(p*16 + r) * 128 + q*8;
      #pragma unroll
      for (int gk = 0; gk < 4; ++gk){
        const bf16x8 ah = ld_frag(weTh + abase + gk*32);
        const bf16x8 al = ld_frag(weTl + abase + gk*32);
        c = MFMA16(ah, bhf[gk], c, 0, 0, 0);
        c = MFMA16(ah, blf[gk], c, 0, 0, 0);
        c = MFMA16(al, bhf[gk], c, 0, 0, 0);
      }
      const float4 w128 = *(const float4*)(we128 + p*16 + q*4);
      const float4 kr   = *(const float4*)(kb + (size_t)row*128 + p*16 + q*4);
      const float4 qc   = *(const float4*)(qb + (size_t)col*128 + p*16 + q*4);
      float al4[4];
      al4[0] = clip5(kr.x*qc.x*0.25f) * (c[0] + dist*w128.x);
      al4[1] = clip5(kr.y*qc.y*0.25f) * (c[1] + dist*w128.y);
      al4[2] = clip5(kr.z*qc.z*0.25f) * (c[2] + dist*w128.z);
      al4[3] = clip5(kr.w*qc.w*0.25f) * (c[3] + dist*w128.w);

      // head-p sum (16 ch = 4 in-lane x 4 q-groups)
      float hs = al4[0]+al4[1]+al4[2]+al4[3];
      hs += __shfl_xor(hs, 16); hs += __shfl_xor(hs, 32);
      const float ax = expf(clip5(hs));

      // scatter
      const float4 vr = *(const float4*)(vb + (size_t)row*128 + p*16 + q*4);
      const size_t wb = (size_t)col*128 + p*16 + q*4;
      atomicAdd(&wV[wb+0], vr.x*ax);
      atomicAdd(&wV[wb+1], vr.y*ax);
      atomicAdd(&wV[wb+2], vr.z*ax);
      atomicAdd(&wV[wb+3], vr.w*ax);
      if (q == 0) atomicAdd(&zz[(size_t)col*H + p], ax);

      // pack alpha -> bf16 hi/lo words for bpermute
      unsigned short th[4], tl[4];
      #pragma unroll
      for (int i = 0; i < 4; ++i){
        th[i] = f2bf(al4[i]);
        tl[i] = f2bf(al4[i] - bf2f(th[i]));
      }
      tw[t][0] = (int)th[0] | ((int)th[1] << 16);
      tw[t][1] = (int)th[2] | ((int)th[3] << 16);
      tw[t][2] = (int)tl[0] | ((int)tl[1] << 16);
      tw[t][3] = (int)tl[2] | ((int)tl[3] << 16);
    }

    // redistribute alpha (D1 layout) -> A2 frag layout via quad permutation
    union { int i[4]; bf16x8 v; } a2h, a2l;
    int u0, u1;
    u0 = __builtin_amdgcn_ds_bpermute(src0, tw[0][0]);
    u1 = __builtin_amdgcn_ds_bpermute(src0, tw[1][0]);
    a2h.i[0] = hisel ? u1 : u0;
    u0 = __builtin_amdgcn_ds_bpermute(src0, tw[0][1]);
    u1 = __builtin_amdgcn_ds_bpermute(src0, tw[1][1]);
    a2h.i[1] = hisel ? u1 : u0;
    u0 = __builtin_amdgcn_ds_bpermute(src1, tw[0][0]);
    u1 = __builtin_amdgcn_ds_bpermute(src1, tw[1][0]);
    a2h.i[2] = hisel ? u1 : u0;
    u0 = __builtin_amdgcn_ds_bpermute(src1, tw[0][1]);
    u1 = __builtin_amdgcn_ds_bpermute(src1, tw[1][1]);
    a2h.i[3] = hisel ? u1 : u0;
    u0 = __builtin_amdgcn_ds_bpermute(src0, tw[0][2]);
    u1 = __builtin_amdgcn_ds_bpermute(src0, tw[1][2]);
    a2l.i[0] = hisel ? u1 : u0;
    u0 = __builtin_amdgcn_ds_bpermute(src0, tw[0][3]);
    u1 = __builtin_amdgcn_ds_bpermute(src0, tw[1][3]);
    a2l.i[1] = hisel ? u1 : u0;
    u0 = __builtin_amdgcn_ds_bpermute(src1, tw[0][2]);
    u1 = __builtin_amdgcn_ds_bpermute(src1, tw[1][2]);
    a2l.i[2] = hisel ? u1 : u0;
    u0 = __builtin_amdgcn_ds_bpermute(src1, tw[0][3]);
    u1 = __builtin_amdgcn_ds_bpermute(src1, tw[1][3]);
    a2l.i[3] = hisel ? u1 : u0;

    // GEMM2 partial: k-window w4
    #pragma unroll
    for (int nt = 0; nt < 8; ++nt){
      const size_t b2base = (size_t)(nt*16 + r)*128 + w4*32 + q*8;
      const bf16x8 b2h = ld_frag(woeTh + b2base);
      const bf16x8 b2l = ld_frag(woeTl + b2base);
      acc[nt] = MFMA16(a2h.v, b2h, acc[nt], 0, 0, 0);
      acc[nt] = MFMA16(a2l.v, b2h, acc[nt], 0, 0, 0);
      acc[nt] = MFMA16(a2h.v, b2l, acc[nt], 0, 0, 0);
    }
  }

  // ---- epilogue: residual + LN2 + stores (D2: edge = ebase+q*4+i, n = nt*16+r)
  float boev[8], g2v[8], b2v[8];
  #pragma unroll
  for (int nt = 0; nt < 8; ++nt){
    boev[nt] = boe[nt*16 + r];
    g2v[nt]  = g2[nt*16 + r];
    b2v[nt]  = b2[nt*16 + r];
  }
  #pragma unroll
  for (int i = 0; i < 4; ++i){
    const int erow = ebase + q*4 + i;
    const size_t base = (size_t)erow * 128;
    float o[8];
    float s2 = 0.f, sq2 = 0.f;
    #pragma unroll
    for (int nt = 0; nt < 8; ++nt){
      o[nt] = acc[nt][i] + ef[base + nt*16 + r] + boev[nt];
      s2 += o[nt]; sq2 += o[nt]*o[nt];
    }
    s2  += __shfl_xor(s2, 1);  s2  += __shfl_xor(s2, 2);
    s2  += __shfl_xor(s2, 4);  s2  += __shfl_xor(s2, 8);
    sq2 += __shfl_xor(sq2, 1); sq2 += __shfl_xor(sq2, 2);
    sq2 += __shfl_xor(sq2, 4); sq2 += __shfl_xor(sq2, 8);
    const float mu2   = s2 * (1.f/128.f);
    const float rstd2 = rsqrtf(sq2 * (1.f/128.f) - mu2*mu2 + LN_EPS);
    #pragma unroll
    for (int nt = 0; nt < 8; ++nt){
      e2_out[base + nt*16 + r] = o[nt];
      const float en = (o[nt] - mu2)*rstd2*g2v[nt] + b2v[nt];
      const unsigned short h = f2bf(en);
      enh[base + nt*16 + r] = h;
      enl[base + nt*16 + r] = f2bf(en - bf2f(h));
    }
  }
}

// ---------------------------------------------------------------------------
// Kernel 4: node attention epilogue; emits hn as bf16 hi/lo.
// ---------------------------------------------------------------------------
__global__ void __launch_bounds__(256)
k_node_final(const float* __restrict__ nf, const float* __restrict__ wV,
             const float* __restrict__ zz,
             const float* __restrict__ Won, const float* __restrict__ bon,
             const float* __restrict__ g2, const float* __restrict__ b2,
             float* __restrict__ h2_out,
             unsigned short* __restrict__ hnh, unsigned short* __restrict__ hnl)
{
  __shared__ __align__(16) float sW[128*128];
  __shared__ __align__(16) float s_h[8][C];
  const int tid = threadIdx.x;
  {
    const float4* a = (const float4*)Won; float4* sa = (float4*)sW;
    for (int i = tid; i < 128*32; i += 256) sa[i] = a[i];
  }
  __syncthreads();
  const int slot = tid >> 5, tg = tid & 31, c0 = tg * 4;
  const float4* sW4 = (const float4*)sW;

  for (int n0 = blockIdx.x * 8; n0 < NN; n0 += gridDim.x * 8){
    const int node = n0 + slot;
    const bool valid = node < NN;
    const size_t nn = valid ? (size_t)node : 0;

    const float4 wv = *(const float4*)(wV + nn * C + c0);
    const float  zh = zz[nn * H + (c0 >> 4)] + 1e-6f;
    {
      float4 ha;
      ha.x = wv.x / zh; ha.y = wv.y / zh; ha.z = wv.z / zh; ha.w = wv.w / zh;
      *(float4*)&s_h[slot][c0] = ha;
    }
    __syncthreads();

    const float4 x  = *(const float4*)(nf + nn * C + c0);
    const float4 bo = *(const float4*)(bon + c0);
    float o0 = x.x + bo.x, o1 = x.y + bo.y, o2 = x.z + bo.z, o3 = x.w + bo.w;
    #pragma unroll 8
    for (int k = 0; k < C; ++k){
      const float hv = s_h[slot][k];
      const float4 w = sW4[k*32 + tg];
      o0 += hv*w.x; o1 += hv*w.y; o2 += hv*w.z; o3 += hv*w.w;
    }

    float s2  = o0 + o1 + o2 + o3;
    float sq2 = o0*o0 + o1*o1 + o2*o2 + o3*o3;
    s2 = red32(s2); sq2 = red32(sq2);
    const float mu2   = s2 * (1.0f / C);
    const float rstd2 = rsqrtf(sq2 * (1.0f / C) - mu2 * mu2 + LN_EPS);
    if (valid){
      float4 o; o.x=o0; o.y=o1; o.z=o2; o.w=o3;
      *(float4*)(h2_out + (size_t)node * C + c0) = o;
      const float4 gg = *(const float4*)(g2 + c0);
      const float4 bb = *(const float4*)(b2 + c0);
      float h0 = (o0 - mu2)*rstd2*gg.x + bb.x;
      float h1 = (o1 - mu2)*rstd2*gg.y + bb.y;
      float h2 = (o2 - mu2)*rstd2*gg.z + bb.z;
      float h3 = (o3 - mu2)*rstd2*gg.w + bb.w;
      ushort4 hh, ll;
      hh.x = f2bf(h0); ll.x = f2bf(h0 - bf2f(hh.x));
      hh.y = f2bf(h1); ll.y = f2bf(h1 - bf2f(hh.y));
      hh.z = f2bf(h2); ll.z = f2bf(h2 - bf2f(hh.z));
      hh.w = f2bf(h3); ll.w = f2bf(h3 - bf2f(hh.w));
      *(ushort4*)(hnh + (size_t)node * C + c0) = hh;
      *(ushort4*)(hnl + (size_t)node * C + c0) = ll;
    }
    __syncthreads();
  }
}

// ---------------------------------------------------------------------------
// Kernel 5: MFMA FFN (validated in round 2).
// ---------------------------------------------------------------------------
__global__ void __launch_bounds__(256, 2)
k_ffn_mfma(int M,
           const unsigned short* __restrict__ xh, const unsigned short* __restrict__ xl,
           const unsigned short* __restrict__ w1h, const unsigned short* __restrict__ w1l,
           const unsigned short* __restrict__ w2h, const unsigned short* __restrict__ w2l,
           float* __restrict__ out)
{
  const int tid  = threadIdx.x;
  const int wid  = tid >> 6;
  const int lane = tid & 63;
  const int r = lane & 15;
  const int q = lane >> 4;
  const int rowbase = (blockIdx.x * 4 + wid) * 32;

  bf16x8 bh[2][4], bl[2][4];
  #pragma unroll
  for (int s = 0; s < 2; ++s){
    int row = rowbase + s*16 + r;
    if (row > M-1) row = M-1;
    const size_t base = (size_t)row * 128 + q * 8;
    #pragma unroll
    for (int gk = 0; gk < 4; ++gk){
      bh[s][gk] = ld_frag(xh + base + gk*32);
      bl[s][gk] = ld_frag(xl + base + gk*32);
    }
  }

  f32x4 acc[2][8];
  #pragma unroll
  for (int s = 0; s < 2; ++s)
    #pragma unroll
    for (int nt = 0; nt < 8; ++nt)
      acc[s][nt] = (f32x4){0.f, 0.f, 0.f, 0.f};

  const int src0 = (r + ((lane & 16) << 1)) << 2;
  const int src1 = src0 + 64;
  const bool hi = (lane >= 32);

  for (int p = 0; p < 8; ++p){
    #pragma unroll
    for (int s = 0; s < 2; ++s){
      int tw[2][4];
      #pragma unroll
      for (int t = 0; t < 2; ++t){
        const size_t abase = (size_t)((2*p + t)*16 + r) * 128 + q*8;
        f32x4 c = (f32x4){0.f, 0.f, 0.f, 0.f};
        #pragma unroll
        for (int gk = 0; gk < 4; ++gk){
          bf16x8 ah = ld_frag(w1h + abase + gk*32);
          bf16x8 al = ld_frag(w1l + abase + gk*32);
          c = MFMA16(ah, bh[s][gk], c, 0, 0, 0);
          c = MFMA16(ah, bl[s][gk], c, 0, 0, 0);
          c = MFMA16(al, bh[s][gk], c, 0, 0, 0);
        }
        unsigned short th[4], tl_[4];
        #pragma unroll
        for (int i = 0; i < 4; ++i){
          float v = c[i];
          v = v / (1.f + __expf(-v));     // silu
          th[i]  = f2bf(v);
          tl_[i] = f2bf(v - bf2f(th[i]));
        }
        tw[t][0] = (int)th[0]  | ((int)th[1]  << 16);
        tw[t][1] = (int)th[2]  | ((int)th[3]  << 16);
        tw[t][2] = (int)tl_[0] | ((int)tl_[1] << 16);
        tw[t][3] = (int)tl_[2] | ((int)tl_[3] << 16);
      }
      int u0, u1;
      union { int i[4]; bf16x8 v; } a2h, a2l;
      u0 = __builtin_amdgcn_ds_bpermute(src0, tw[0][0]);
      u1 = __builtin_amdgcn_ds_bpermute(src0, tw[1][0]);
      a2h.i[0] = hi ? u1 : u0;
      u0 = __builtin_amdgcn_ds_bpermute(src0, tw[0][1]);
      u1 = __builtin_amdgcn_ds_bpermute(src0, tw[1][1]);
      a2h.i[1] = hi ? u1 : u0;
      u0 = __builtin_amdgcn_ds_bpermute(src1, tw[0][0]);
      u1 = __builtin_amdgcn_ds_bpermute(src1, tw[1][0]);
      a2h.i[2] = hi ? u1 : u0;
      u0 = __builtin_amdgcn_ds_bpermute(src1, tw[0][1]);
      u1 = __builtin_amdgcn_ds_bpermute(src1, tw[1][1]);
      a2h.i[3] = hi ? u1 : u0;
      u0 = __builtin_amdgcn_ds_bpermute(src0, tw[0][2]);
      u1 = __builtin_amdgcn_ds_bpermute(src0, tw[1][2]);
      a2l.i[0] = hi ? u1 : u0;
      u0 = __builtin_amdgcn_ds_bpermute(src0, tw[0][3]);
      u1 = __builtin_amdgcn_ds_bpermute(src0, tw[1][3]);
      a2l.i[1] = hi ? u1 : u0;
      u0 = __builtin_amdgcn_ds_bpermute(src1, tw[0][2]);
      u1 = __builtin_amdgcn_ds_bpermute(src1, tw[1][2]);
      a2l.i[2] = hi ? u1 : u0;
      u0 = __builtin_amdgcn_ds_bpermute(src1, tw[0][3]);
      u1 = __builtin_amdgcn_ds_bpermute(src1, tw[1][3]);
      a2l.i[3] = hi ? u1 : u0;

      #pragma unroll
      for (int nt = 0; nt < 8; ++nt){
        const size_t b2base = (size_t)(nt*16 + r) * 256 + p*32 + q*8;
        bf16x8 b2h = ld_frag(w2h + b2base);
        bf16x8 b2l = ld_frag(w2l + b2base);
        acc[s][nt] = MFMA16(a2h.v, b2h, acc[s][nt], 0, 0, 0);
        acc[s][nt] = MFMA16(a2l.v, b2h, acc[s][nt], 0, 0, 0);
        acc[s][nt] = MFMA16(a2h.v, b2l, acc[s][nt], 0, 0, 0);
      }
    }
  }

  #pragma unroll
  for (int s = 0; s < 2; ++s){
    #pragma unroll
    for (int nt = 0; nt < 8; ++nt){
      #pragma unroll
      for (int i = 0; i < 4; ++i){
        const int row = rowbase + s*16 + q*4 + i;
        if (row < M){
          const size_t idx = (size_t)row * 128 + nt*16 + r;
          out[idx] += acc[s][nt][i];
        }
      }
    }
  }
}

// ---------------------------------------------------------------------------
extern "C" void kernel_launch(void* const* d_in, const int* in_sizes, int n_in,
                              void* d_out, int out_size, void* d_ws, size_t ws_size,
                              hipStream_t stream)
{
  const float* nf     = (const float*)d_in[0];
  const float* ef     = (const float*)d_in[1];
  const float* coords = (const float*)d_in[2];
  const int*   eidx   = (const int*)  d_in[3];
  const float* Wq     = (const float*)d_in[4];
  const float* Wk     = (const float*)d_in[5];
  const float* Wv     = (const float*)d_in[6];
  const float* We     = (const float*)d_in[7];
  const float* Won    = (const float*)d_in[8];
  const float* bon    = (const float*)d_in[9];
  const float* Woe    = (const float*)d_in[10];
  const float* boe    = (const float*)d_in[11];
  const float* ln1ng  = (const float*)d_in[12];
  const float* ln1nb  = (const float*)d_in[13];
  const float* ln1eg  = (const float*)d_in[14];
  const float* ln1eb  = (const float*)d_in[15];
  const float* ln2ng  = (const float*)d_in[16];
  const float* ln2nb  = (const float*)d_in[17];
  const float* ln2eg  = (const float*)d_in[18];
  const float* ln2eb  = (const float*)d_in[19];
  const float* Wn1    = (const float*)d_in[20];
  const float* Wn2    = (const float*)d_in[21];
  const float* We1    = (const float*)d_in[22];
  const float* We2    = (const float*)d_in[23];

  float* out_h = (float*)d_out;
  float* out_e = out_h + (size_t)NN * C;

  float* ws = (float*)d_ws;
  float* qb = ws;
  float* kb = qb + (size_t)NN * C;
  float* vb = kb + (size_t)NN * C;
  float* wV = vb + (size_t)NN * C;
  float* zz = wV + (size_t)NN * C;            // [NN, H]
  unsigned short* hnh = (unsigned short*)(zz + (size_t)NN * H);
  unsigned short* hnl = hnh + (size_t)NN * C;
  unsigned short* enh = hnl + (size_t)NN * C;
  unsigned short* enl = enh + (size_t)NE * C;
  unsigned short* wts = enl + (size_t)NE * C; // 8 x 32768
  unsigned short* wn1h = wts + 0*32768;
  unsigned short* wn1l = wts + 1*32768;
  unsigned short* wn2h = wts + 2*32768;
  unsigned short* wn2l = wts + 3*32768;
  unsigned short* we1h = wts + 4*32768;
  unsigned short* we1l = wts + 5*32768;
  unsigned short* we2h = wts + 6*32768;
  unsigned short* we2l = wts + 7*32768;
  unsigned short* weTh  = wts + 8*32768;
  unsigned short* weTl  = weTh + 16384;
  unsigned short* woeTh = weTl + 16384;
  unsigned short* woeTl = woeTh + 16384;
  float*          we128 = (float*)(woeTl + 16384);

  hipLaunchKernelGGL(k_prep, dim3(641), dim3(256), 0, stream,
                     Wn1, Wn2, We1, We2, We, Woe,
                     wts, weTh, weTl, woeTh, woeTl, we128);
  hipLaunchKernelGGL(k_node_ln_qkv, dim3((NN + 7) / 8), dim3(256), 0, stream,
                     nf, Wq, Wk, Wv, ln1ng, ln1nb, qb, kb, vb);
  hipLaunchKernelGGL(k_zero, dim3(1024), dim3(256), 0, stream,
                     wV, (size_t)NN * C + (size_t)NN * H);
  hipLaunchKernelGGL(k_edge_mfma, dim3(NE / 64), dim3(256), 0, stream,
                     ef, coords, eidx, qb, kb, vb,
                     weTh, weTl, we128, woeTh, woeTl, boe,
                     ln1eg, ln1eb, ln2eg, ln2eb,
                     wV, zz, out_e, enh, enl);
  hipLaunchKernelGGL(k_node_final, dim3(1024), dim3(256), 0, stream,
                     nf, wV, zz, Won, bon, ln2ng, ln2nb, out_h, hnh, hnl);
  hipLaunchKernelGGL(k_ffn_mfma, dim3((NN + 127) / 128), dim3(256), 0, stream,
                     NN, hnh, hnl, wn1h, wn1l, wn2h, wn2l, out_h);
  hipLaunchKernelGGL(k_ffn_mfma, dim3((NE + 127) / 128), dim3(256), 0, stream,
                     NE, enh, enl, we1h, we1l, we2h, we2l, out_e);
}

// Round 10
// 2770.604 us; speedup vs baseline: 2.4593x; 1.1550x over previous
//
#include <hip/hip_runtime.h>
#include <math.h>

#define NN 50000
#define NE 600000
#define C 128
#define H 8
#define LN_EPS 1e-5f
#define NB1 196   // ceil(NN/256)

typedef __attribute__((ext_vector_type(8))) short bf16x8;
typedef __attribute__((ext_vector_type(4))) float f32x4;
#define MFMA16 __builtin_amdgcn_mfma_f32_16x16x32_bf16

__device__ __forceinline__ float clip5(float x){ return fminf(fmaxf(x, -5.f), 5.f); }

__device__ __forceinline__ float red32(float v){
  v += __shfl_xor(v, 1);  v += __shfl_xor(v, 2);  v += __shfl_xor(v, 4);
  v += __shfl_xor(v, 8);  v += __shfl_xor(v, 16);
  return v;
}

// manual RNE float->bf16 (bits) and back
__device__ __forceinline__ unsigned short f2bf(float f){
  union { float f; unsigned u; } c; c.f = f;
  unsigned r = (c.u + 0x7fffu + ((c.u >> 16) & 1u)) >> 16;
  return (unsigned short)r;
}
__device__ __forceinline__ float bf2f(unsigned short u){
  union { unsigned u; float f; } c; c.u = ((unsigned)u) << 16;
  return c.f;
}

__device__ __forceinline__ bf16x8 ld_frag(const unsigned short* p){
  return *(const bf16x8*)p;
}

// ---------------------------------------------------------------------------
// Kernel 1: node LN1 + fused QKV projection.  8 nodes / 256-thread block.
// ---------------------------------------------------------------------------
__global__ void __launch_bounds__(256)
k_node_ln_qkv(const float* __restrict__ nf,
              const float* __restrict__ Wq, const float* __restrict__ Wk,
              const float* __restrict__ Wv,
              const float* __restrict__ g, const float* __restrict__ b,
              float* __restrict__ qb, float* __restrict__ kb, float* __restrict__ vb)
{
  __shared__ __align__(16) float s_h[8][C];
  const int tid = threadIdx.x;
  const int slot = tid >> 5, tg = tid & 31, c0 = tg * 4;
  const int node = blockIdx.x * 8 + slot;
  const bool valid = node < NN;
  const size_t nn = valid ? (size_t)node : 0;

  const float4 x = *(const float4*)(nf + nn * C + c0);
  float s  = x.x + x.y + x.z + x.w;
  float sq = x.x*x.x + x.y*x.y + x.z*x.z + x.w*x.w;
  s = red32(s); sq = red32(sq);
  const float mu   = s * (1.0f / C);
  const float rstd = rsqrtf(sq * (1.0f / C) - mu * mu + LN_EPS);
  const float4 gg = *(const float4*)(g + c0);
  const float4 bb = *(const float4*)(b + c0);
  float4 hv;
  hv.x = (x.x - mu) * rstd * gg.x + bb.x;
  hv.y = (x.y - mu) * rstd * gg.y + bb.y;
  hv.z = (x.z - mu) * rstd * gg.z + bb.z;
  hv.w = (x.w - mu) * rstd * gg.w + bb.w;
  *(float4*)&s_h[slot][c0] = hv;
  __syncthreads();

  const float4* Wq4 = (const float4*)Wq;
  const float4* Wk4 = (const float4*)Wk;
  const float4* Wv4 = (const float4*)Wv;
  float aq0=0,aq1=0,aq2=0,aq3=0, ak0=0,ak1=0,ak2=0,ak3=0, av0=0,av1=0,av2=0,av3=0;
  #pragma unroll 8
  for (int k = 0; k < C; ++k){
    const float h = s_h[slot][k];
    const float4 wq = Wq4[k*32 + tg];
    const float4 wk = Wk4[k*32 + tg];
    const float4 wv = Wv4[k*32 + tg];
    aq0 += h*wq.x; aq1 += h*wq.y; aq2 += h*wq.z; aq3 += h*wq.w;
    ak0 += h*wk.x; ak1 += h*wk.y; ak2 += h*wk.z; ak3 += h*wk.w;
    av0 += h*wv.x; av1 += h*wv.y; av2 += h*wv.z; av3 += h*wv.w;
  }
  if (valid){
    float4 o;
    o.x=aq0; o.y=aq1; o.z=aq2; o.w=aq3; *(float4*)(qb + nn*C + c0) = o;
    o.x=ak0; o.y=ak1; o.z=ak2; o.w=ak3; *(float4*)(kb + nn*C + c0) = o;
    o.x=av0; o.y=av1; o.z=av2; o.w=av3; *(float4*)(vb + nn*C + c0) = o;
  }
}

// ---------------------------------------------------------------------------
__global__ void k_zero(float* __restrict__ p, size_t n){
  size_t i = (size_t)blockIdx.x * blockDim.x + threadIdx.x;
  const size_t st = (size_t)gridDim.x * blockDim.x;
  for (; i < n; i += st) p[i] = 0.f;
}

// ---------------------------------------------------------------------------
// Prep: transposed + hi/lo-split bf16 copies of FFN weights, WeT, WoeT,
// and the dist row We[128] fp32.
// ---------------------------------------------------------------------------
__global__ void __launch_bounds__(256)
k_prep(const float* __restrict__ Wn1, const float* __restrict__ Wn2,
       const float* __restrict__ We1, const float* __restrict__ We2,
       const float* __restrict__ We,  const float* __restrict__ Woe,
       unsigned short* __restrict__ o,
       unsigned short* __restrict__ weTh, unsigned short* __restrict__ weTl,
       unsigned short* __restrict__ woeTh, unsigned short* __restrict__ woeTl,
       float* __restrict__ we128f)
{
  const int id = blockIdx.x * 256 + threadIdx.x;
  if (id < 131072){
    const int w = id >> 15, e = id & 32767;
    const float* src; int K, Nn;
    if      (w == 0){ src = Wn1; K = 128; Nn = 256; }
    else if (w == 1){ src = Wn2; K = 256; Nn = 128; }
    else if (w == 2){ src = We1; K = 128; Nn = 256; }
    else            { src = We2; K = 256; Nn = 128; }
    const int n = (K == 128) ? (e >> 7) : (e >> 8);
    const int k = e - n * K;
    const float v = src[(size_t)k * Nn + n];
    const unsigned short h = f2bf(v);
    const unsigned short l = f2bf(v - bf2f(h));
    unsigned short* oh = o + (size_t)w * 65536;
    oh[e] = h;
    oh[32768 + e] = l;
  } else if (id < 147456){
    const int e = id - 131072;
    const int n = e >> 7, k = e & 127;
    const float v = We[(size_t)k * 128 + n];
    const unsigned short h = f2bf(v);
    weTh[e] = h; weTl[e] = f2bf(v - bf2f(h));
  } else if (id < 163840){
    const int e = id - 147456;
    const int n = e >> 7, k = e & 127;
    const float v = Woe[(size_t)k * 128 + n];
    const unsigned short h = f2bf(v);
    woeTh[e] = h; woeTl[e] = f2bf(v - bf2f(h));
  } else if (id < 163968){
    const int c = id - 163840;
    we128f[c] = We[128 * 128 + c];
  }
}

// ---------------------------------------------------------------------------
// CSR build: histogram -> block scan (3 phases) -> cursor fill.
// ---------------------------------------------------------------------------
__global__ void __launch_bounds__(256)
k_count(const int* __restrict__ eidx, int* __restrict__ deg){
  const int e = blockIdx.x * 256 + threadIdx.x;
  if (e < NE) atomicAdd(&deg[eidx[NE + e]], 1);
}

__global__ void __launch_bounds__(256)
k_scan1(const int* __restrict__ deg, int* __restrict__ ex, int* __restrict__ bsum){
  __shared__ int sd[256];
  const int i = threadIdx.x;
  const int t = blockIdx.x * 256 + i;
  const int v = (t < NN) ? deg[t] : 0;
  sd[i] = v;
  __syncthreads();
  for (int off = 1; off < 256; off <<= 1){
    const int add = (i >= off) ? sd[i - off] : 0;
    __syncthreads();
    sd[i] += add;
    __syncthreads();
  }
  if (t < NN) ex[t] = sd[i] - v;            // exclusive prefix within block
  if (i == 255) bsum[blockIdx.x] = sd[255]; // block total
}

__global__ void __launch_bounds__(256)
k_scan2(const int* __restrict__ bsum, int* __restrict__ bpre){
  __shared__ int sd[256];
  const int i = threadIdx.x;
  const int v = (i < NB1) ? bsum[i] : 0;
  sd[i] = v;
  __syncthreads();
  for (int off = 1; off < 256; off <<= 1){
    const int add = (i >= off) ? sd[i - off] : 0;
    __syncthreads();
    sd[i] += add;
    __syncthreads();
  }
  if (i < NB1) bpre[i] = sd[i] - v;
}

__global__ void __launch_bounds__(256)
k_scan3(const int* __restrict__ ex, const int* __restrict__ bpre,
        int* __restrict__ rowptr, int* __restrict__ cursor){
  const int t = blockIdx.x * 256 + threadIdx.x;
  if (t < NN){
    const int r = ex[t] + bpre[t >> 8];
    rowptr[t] = r;
    cursor[t] = r;
    if (t == 0) rowptr[NN] = NE;
  }
}

__global__ void __launch_bounds__(256)
k_fill(const int* __restrict__ eidx, int* __restrict__ cursor, int* __restrict__ csr){
  const int e = blockIdx.x * 256 + threadIdx.x;
  if (e < NE){
    const int col = eidx[NE + e];
    const int pos = atomicAdd(&cursor[col], 1);
    csr[pos] = e;
  }
}

// ---------------------------------------------------------------------------
// Gather: one wave per node, lane owns 2 channels.  wV = sum(ax * v[row]),
// z = sum(ax).  Deterministic fp32 register accumulation, no atomics.
// ---------------------------------------------------------------------------
__global__ void __launch_bounds__(256)
k_gather(const int* __restrict__ rowptr, const int* __restrict__ csr,
         const int* __restrict__ eidx, const float* __restrict__ vb,
         const float* __restrict__ axbuf,
         float* __restrict__ wV, float* __restrict__ zz)
{
  const int wid = threadIdx.x >> 6, lane = threadIdx.x & 63;
  const int n = blockIdx.x * 4 + wid;
  if (n >= NN) return;
  const int s = rowptr[n], t = rowptr[n + 1];
  const int c0 = lane * 2, h = lane >> 3;   // channels c0,c0+1 belong to head h
  float a0 = 0.f, a1 = 0.f, zacc = 0.f;
  for (int p = s; p < t; ++p){
    const int eid = csr[p];
    const int row = eidx[eid];
    const float ax = axbuf[(size_t)eid * 8 + h];
    const float2 vv = *(const float2*)(vb + (size_t)row * 128 + c0);
    a0 += vv.x * ax; a1 += vv.y * ax;
    if (lane < 8) zacc += axbuf[(size_t)eid * 8 + lane];
  }
  wV[(size_t)n * 128 + c0]     = a0;
  wV[(size_t)n * 128 + c0 + 1] = a1;
  if (lane < 8) zz[(size_t)n * 8 + lane] = zacc;
}

// ---------------------------------------------------------------------------
// Kernel 3: MFMA edge pipeline (atomics removed; writes ax[e][h] instead).
// 16 edges/wave, 64 edges/block, zero LDS.
// ---------------------------------------------------------------------------
__global__ void __launch_bounds__(256, 2)
k_edge_mfma(const float* __restrict__ ef, const float* __restrict__ coords,
            const int* __restrict__ eidx,
            const float* __restrict__ qb, const float* __restrict__ kb,
            const unsigned short* __restrict__ weTh, const unsigned short* __restrict__ weTl,
            const float* __restrict__ we128,
            const unsigned short* __restrict__ woeTh, const unsigned short* __restrict__ woeTl,
            const float* __restrict__ boe,
            const float* __restrict__ g1, const float* __restrict__ b1,
            const float* __restrict__ g2, const float* __restrict__ b2,
            float* __restrict__ axbuf,
            float* __restrict__ e2_out,
            unsigned short* __restrict__ enh, unsigned short* __restrict__ enl)
{
  const int tid  = threadIdx.x;
  const int wid  = tid >> 6;
  const int lane = tid & 63;
  const int r = lane & 15, q = lane >> 4;
  const int ebase = (blockIdx.x * 4 + wid) * 16;   // NE % 64 == 0: no tail
  const int edge  = ebase + r;
  const size_t e128 = (size_t)edge * 128;

  // ---- load ef slice + LN1 stats (reduce across q via shfl_xor 16,32) ----
  float xv[32];
  #pragma unroll
  for (int gk = 0; gk < 4; ++gk){
    const float4 a = *(const float4*)(ef + e128 + gk*32 + q*8);
    const float4 b = *(const float4*)(ef + e128 + gk*32 + q*8 + 4);
    xv[gk*8+0]=a.x; xv[gk*8+1]=a.y; xv[gk*8+2]=a.z; xv[gk*8+3]=a.w;
    xv[gk*8+4]=b.x; xv[gk*8+5]=b.y; xv[gk*8+6]=b.z; xv[gk*8+7]=b.w;
  }
  float s = 0.f, sq = 0.f;
  #pragma unroll
  for (int j = 0; j < 32; ++j){ s += xv[j]; sq += xv[j]*xv[j]; }
  s  += __shfl_xor(s, 16);  s  += __shfl_xor(s, 32);
  sq += __shfl_xor(sq, 16); sq += __shfl_xor(sq, 32);
  const float mu   = s * (1.f/128.f);
  const float rstd = rsqrtf(sq * (1.f/128.f) - mu*mu + LN_EPS);

  bf16x8 bhf[4], blf[4];
  #pragma unroll
  for (int gk = 0; gk < 4; ++gk){
    const float4 ga = *(const float4*)(g1 + gk*32 + q*8);
    const float4 gb = *(const float4*)(g1 + gk*32 + q*8 + 4);
    const float4 ba = *(const float4*)(b1 + gk*32 + q*8);
    const float4 bb = *(const float4*)(b1 + gk*32 + q*8 + 4);
    const float gv[8] = {ga.x,ga.y,ga.z,ga.w,gb.x,gb.y,gb.z,gb.w};
    const float bv[8] = {ba.x,ba.y,ba.z,ba.w,bb.x,bb.y,bb.z,bb.w};
    union { unsigned short u[8]; bf16x8 v; } ph, pl;
    #pragma unroll
    for (int j = 0; j < 8; ++j){
      const float e = (xv[gk*8+j] - mu) * rstd * gv[j] + bv[j];
      ph.u[j] = f2bf(e);
      pl.u[j] = f2bf(e - bf2f(ph.u[j]));
    }
    bhf[gk] = ph.v; blf[gk] = pl.v;
  }

  // ---- edge meta (lane-local: this lane's edge = ebase + r) ----
  const int row = eidx[edge];
  const int col = eidx[NE + edge];
  float dist;
  {
    const size_t r3 = (size_t)row*3, c3 = (size_t)col*3;
    const float dx = coords[r3+0]-coords[c3+0];
    const float dy = coords[r3+1]-coords[c3+1];
    const float dz = coords[r3+2]-coords[c3+2];
    dist = 0.1f * sqrtf(dx*dx + dy*dy + dz*dz);
  }

  const int src0 = (r + ((lane & 16) << 1)) << 2;
  const int src1 = src0 + 64;
  const bool hisel = (lane >= 32);

  f32x4 acc[8];
  #pragma unroll
  for (int nt = 0; nt < 8; ++nt) acc[nt] = (f32x4){0.f,0.f,0.f,0.f};

  #pragma unroll
  for (int w4 = 0; w4 < 4; ++w4){
    int tw[2][4];
    #pragma unroll
    for (int t = 0; t < 2; ++t){
      const int p = 2*w4 + t;
      // GEMM1 tile p: ep channels p*16+q*4+i for edge ebase+r
      f32x4 c = (f32x4){0.f,0.f,0.f,0.f};
      const size_t abase = (size_t)(p*16 + r) * 128 + q*8;
      #pragma unroll
      for (int gk = 0; gk < 4; ++gk){
        const bf16x8 ah = ld_frag(weTh + abase + gk*32);
        const bf16x8 al = ld_frag(weTl + abase + gk*32);
        c = MFMA16(ah, bhf[gk], c, 0, 0, 0);
        c = MFMA16(ah, blf[gk], c, 0, 0, 0);
        c = MFMA16(al, bhf[gk], c, 0, 0, 0);
      }
      const float4 w128 = *(const float4*)(we128 + p*16 + q*4);
      const float4 kr   = *(const float4*)(kb + (size_t)row*128 + p*16 + q*4);
      const float4 qc   = *(const float4*)(qb + (size_t)col*128 + p*16 + q*4);
      float al4[4];
      al4[0] = clip5(kr.x*qc.x*0.25f) * (c[0] + dist*w128.x);
      al4[1] = clip5(kr.y*qc.y*0.25f) * (c[1] + dist*w128.y);
      al4[2] = clip5(kr.z*qc.z*0.25f) * (c[2] + dist*w128.z);
      al4[3] = clip5(kr.w*qc.w*0.25f) * (c[3] + dist*w128.w);

      // head-p sum (16 ch = 4 in-lane x 4 q-groups)
      float hs = al4[0]+al4[1]+al4[2]+al4[3];
      hs += __shfl_xor(hs, 16); hs += __shfl_xor(hs, 32);
      const float ax = expf(clip5(hs));

      // store per-edge attention weight (replaces atomic scatter)
      if (q == 0) axbuf[(size_t)edge * 8 + p] = ax;

      // pack alpha -> bf16 hi/lo words for bpermute
      unsigned short th[4], tl[4];
      #pragma unroll
      for (int i = 0; i < 4; ++i){
        th[i] = f2bf(al4[i]);
        tl[i] = f2bf(al4[i] - bf2f(th[i]));
      }
      tw[t][0] = (int)th[0] | ((int)th[1] << 16);
      tw[t][1] = (int)th[2] | ((int)th[3] << 16);
      tw[t][2] = (int)tl[0] | ((int)tl[1] << 16);
      tw[t][3] = (int)tl[2] | ((int)tl[3] << 16);
    }

    // redistribute alpha (D1 layout) -> A2 frag layout via quad permutation
    union { int i[4]; bf16x8 v; } a2h, a2l;
    int u0, u1;
    u0 = __builtin_amdgcn_ds_bpermute(src0, tw[0][0]);
    u1 = __builtin_amdgcn_ds_bpermute(src0, tw[1][0]);
    a2h.i[0] = hisel ? u1 : u0;
    u0 = __builtin_amdgcn_ds_bpermute(src0, tw[0][1]);
    u1 = __builtin_amdgcn_ds_bpermute(src0, tw[1][1]);
    a2h.i[1] = hisel ? u1 : u0;
    u0 = __builtin_amdgcn_ds_bpermute(src1, tw[0][0]);
    u1 = __builtin_amdgcn_ds_bpermute(src1, tw[1][0]);
    a2h.i[2] = hisel ? u1 : u0;
    u0 = __builtin_amdgcn_ds_bpermute(src1, tw[0][1]);
    u1 = __builtin_amdgcn_ds_bpermute(src1, tw[1][1]);
    a2h.i[3] = hisel ? u1 : u0;
    u0 = __builtin_amdgcn_ds_bpermute(src0, tw[0][2]);
    u1 = __builtin_amdgcn_ds_bpermute(src0, tw[1][2]);
    a2l.i[0] = hisel ? u1 : u0;
    u0 = __builtin_amdgcn_ds_bpermute(src0, tw[0][3]);
    u1 = __builtin_amdgcn_ds_bpermute(src0, tw[1][3]);
    a2l.i[1] = hisel ? u1 : u0;
    u0 = __builtin_amdgcn_ds_bpermute(src1, tw[0][2]);
    u1 = __builtin_amdgcn_ds_bpermute(src1, tw[1][2]);
    a2l.i[2] = hisel ? u1 : u0;
    u0 = __builtin_amdgcn_ds_bpermute(src1, tw[0][3]);
    u1 = __builtin_amdgcn_ds_bpermute(src1, tw[1][3]);
    a2l.i[3] = hisel ? u1 : u0;

    // GEMM2 partial: k-window w4
    #pragma unroll
    for (int nt = 0; nt < 8; ++nt){
      const size_t b2base = (size_t)(nt*16 + r)*128 + w4*32 + q*8;
      const bf16x8 b2h = ld_frag(woeTh + b2base);
      const bf16x8 b2l = ld_frag(woeTl + b2base);
      acc[nt] = MFMA16(a2h.v, b2h, acc[nt], 0, 0, 0);
      acc[nt] = MFMA16(a2l.v, b2h, acc[nt], 0, 0, 0);
      acc[nt] = MFMA16(a2h.v, b2l, acc[nt], 0, 0, 0);
    }
  }

  // ---- epilogue: residual + LN2 + stores (D2: edge = ebase+q*4+i, n = nt*16+r)
  float boev[8], g2v[8], b2v[8];
  #pragma unroll
  for (int nt = 0; nt < 8; ++nt){
    boev[nt] = boe[nt*16 + r];
    g2v[nt]  = g2[nt*16 + r];
    b2v[nt]  = b2[nt*16 + r];
  }
  #pragma unroll
  for (int i = 0; i < 4; ++i){
    const int erow = ebase + q*4 + i;
    const size_t base = (size_t)erow * 128;
    float o[8];
    float s2 = 0.f, sq2 = 0.f;
    #pragma unroll
    for (int nt = 0; nt < 8; ++nt){
      o[nt] = acc[nt][i] + ef[base + nt*16 + r] + boev[nt];
      s2 += o[nt]; sq2 += o[nt]*o[nt];
    }
    s2  += __shfl_xor(s2, 1);  s2  += __shfl_xor(s2, 2);
    s2  += __shfl_xor(s2, 4);  s2  += __shfl_xor(s2, 8);
    sq2 += __shfl_xor(sq2, 1); sq2 += __shfl_xor(sq2, 2);
    sq2 += __shfl_xor(sq2, 4); sq2 += __shfl_xor(sq2, 8);
    const float mu2   = s2 * (1.f/128.f);
    const float rstd2 = rsqrtf(sq2 * (1.f/128.f) - mu2*mu2 + LN_EPS);
    #pragma unroll
    for (int nt = 0; nt < 8; ++nt){
      e2_out[base + nt*16 + r] = o[nt];
      const float en = (o[nt] - mu2)*rstd2*g2v[nt] + b2v[nt];
      const unsigned short h = f2bf(en);
      enh[base + nt*16 + r] = h;
      enl[base + nt*16 + r] = f2bf(en - bf2f(h));
    }
  }
}

// ---------------------------------------------------------------------------
// Kernel 4: node attention epilogue; emits hn as bf16 hi/lo.
// ---------------------------------------------------------------------------
__global__ void __launch_bounds__(256)
k_node_final(const float* __restrict__ nf, const float* __restrict__ wV,
             const float* __restrict__ zz,
             const float* __restrict__ Won, const float* __restrict__ bon,
             const float* __restrict__ g2, const float* __restrict__ b2,
             float* __restrict__ h2_out,
             unsigned short* __restrict__ hnh, unsigned short* __restrict__ hnl)
{
  __shared__ __align__(16) float sW[128*128];
  __shared__ __align__(16) float s_h[8][C];
  const int tid = threadIdx.x;
  {
    const float4* a = (const float4*)Won; float4* sa = (float4*)sW;
    for (int i = tid; i < 128*32; i += 256) sa[i] = a[i];
  }
  __syncthreads();
  const int slot = tid >> 5, tg = tid & 31, c0 = tg * 4;
  const float4* sW4 = (const float4*)sW;

  for (int n0 = blockIdx.x * 8; n0 < NN; n0 += gridDim.x * 8){
    const int node = n0 + slot;
    const bool valid = node < NN;
    const size_t nn = valid ? (size_t)node : 0;

    const float4 wv = *(const float4*)(wV + nn * C + c0);
    const float  zh = zz[nn * H + (c0 >> 4)] + 1e-6f;
    {
      float4 ha;
      ha.x = wv.x / zh; ha.y = wv.y / zh; ha.z = wv.z / zh; ha.w = wv.w / zh;
      *(float4*)&s_h[slot][c0] = ha;
    }
    __syncthreads();

    const float4 x  = *(const float4*)(nf + nn * C + c0);
    const float4 bo = *(const float4*)(bon + c0);
    float o0 = x.x + bo.x, o1 = x.y + bo.y, o2 = x.z + bo.z, o3 = x.w + bo.w;
    #pragma unroll 8
    for (int k = 0; k < C; ++k){
      const float hv = s_h[slot][k];
      const float4 w = sW4[k*32 + tg];
      o0 += hv*w.x; o1 += hv*w.y; o2 += hv*w.z; o3 += hv*w.w;
    }

    float s2  = o0 + o1 + o2 + o3;
    float sq2 = o0*o0 + o1*o1 + o2*o2 + o3*o3;
    s2 = red32(s2); sq2 = red32(sq2);
    const float mu2   = s2 * (1.0f / C);
    const float rstd2 = rsqrtf(sq2 * (1.0f / C) - mu2 * mu2 + LN_EPS);
    if (valid){
      float4 o; o.x=o0; o.y=o1; o.z=o2; o.w=o3;
      *(float4*)(h2_out + (size_t)node * C + c0) = o;
      const float4 gg = *(const float4*)(g2 + c0);
      const float4 bb = *(const float4*)(b2 + c0);
      float h0 = (o0 - mu2)*rstd2*gg.x + bb.x;
      float h1 = (o1 - mu2)*rstd2*gg.y + bb.y;
      float h2 = (o2 - mu2)*rstd2*gg.z + bb.z;
      float h3 = (o3 - mu2)*rstd2*gg.w + bb.w;
      ushort4 hh, ll;
      hh.x = f2bf(h0); ll.x = f2bf(h0 - bf2f(hh.x));
      hh.y = f2bf(h1); ll.y = f2bf(h1 - bf2f(hh.y));
      hh.z = f2bf(h2); ll.z = f2bf(h2 - bf2f(hh.z));
      hh.w = f2bf(h3); ll.w = f2bf(h3 - bf2f(hh.w));
      *(ushort4*)(hnh + (size_t)node * C + c0) = hh;
      *(ushort4*)(hnl + (size_t)node * C + c0) = ll;
    }
    __syncthreads();
  }
}

// ---------------------------------------------------------------------------
// Kernel 5: MFMA FFN (validated in round 2).
// ---------------------------------------------------------------------------
__global__ void __launch_bounds__(256, 2)
k_ffn_mfma(int M,
           const unsigned short* __restrict__ xh, const unsigned short* __restrict__ xl,
           const unsigned short* __restrict__ w1h, const unsigned short* __restrict__ w1l,
           const unsigned short* __restrict__ w2h, const unsigned short* __restrict__ w2l,
           float* __restrict__ out)
{
  const int tid  = threadIdx.x;
  const int wid  = tid >> 6;
  const int lane = tid & 63;
  const int r = lane & 15;
  const int q = lane >> 4;
  const int rowbase = (blockIdx.x * 4 + wid) * 32;

  bf16x8 bh[2][4], bl[2][4];
  #pragma unroll
  for (int s = 0; s < 2; ++s){
    int row = rowbase + s*16 + r;
    if (row > M-1) row = M-1;
    const size_t base = (size_t)row * 128 + q * 8;
    #pragma unroll
    for (int gk = 0; gk < 4; ++gk){
      bh[s][gk] = ld_frag(xh + base + gk*32);
      bl[s][gk] = ld_frag(xl + base + gk*32);
    }
  }

  f32x4 acc[2][8];
  #pragma unroll
  for (int s = 0; s < 2; ++s)
    #pragma unroll
    for (int nt = 0; nt < 8; ++nt)
      acc[s][nt] = (f32x4){0.f, 0.f, 0.f, 0.f};

  const int src0 = (r + ((lane & 16) << 1)) << 2;
  const int src1 = src0 + 64;
  const bool hi = (lane >= 32);

  for (int p = 0; p < 8; ++p){
    #pragma unroll
    for (int s = 0; s < 2; ++s){
      int tw[2][4];
      #pragma unroll
      for (int t = 0; t < 2; ++t){
        const size_t abase = (size_t)((2*p + t)*16 + r) * 128 + q*8;
        f32x4 c = (f32x4){0.f, 0.f, 0.f, 0.f};
        #pragma unroll
        for (int gk = 0; gk < 4; ++gk){
          bf16x8 ah = ld_frag(w1h + abase + gk*32);
          bf16x8 al = ld_frag(w1l + abase + gk*32);
          c = MFMA16(ah, bh[s][gk], c, 0, 0, 0);
          c = MFMA16(ah, bl[s][gk], c, 0, 0, 0);
          c = MFMA16(al, bh[s][gk], c, 0, 0, 0);
        }
        unsigned short th[4], tl_[4];
        #pragma unroll
        for (int i = 0; i < 4; ++i){
          float v = c[i];
          v = v / (1.f + __expf(-v));     // silu
          th[i]  = f2bf(v);
          tl_[i] = f2bf(v - bf2f(th[i]));
        }
        tw[t][0] = (int)th[0]  | ((int)th[1]  << 16);
        tw[t][1] = (int)th[2]  | ((int)th[3]  << 16);
        tw[t][2] = (int)tl_[0] | ((int)tl_[1] << 16);
        tw[t][3] = (int)tl_[2] | ((int)tl_[3] << 16);
      }
      int u0, u1;
      union { int i[4]; bf16x8 v; } a2h, a2l;
      u0 = __builtin_amdgcn_ds_bpermute(src0, tw[0][0]);
      u1 = __builtin_amdgcn_ds_bpermute(src0, tw[1][0]);
      a2h.i[0] = hi ? u1 : u0;
      u0 = __builtin_amdgcn_ds_bpermute(src0, tw[0][1]);
      u1 = __builtin_amdgcn_ds_bpermute(src0, tw[1][1]);
      a2h.i[1] = hi ? u1 : u0;
      u0 = __builtin_amdgcn_ds_bpermute(src1, tw[0][0]);
      u1 = __builtin_amdgcn_ds_bpermute(src1, tw[1][0]);
      a2h.i[2] = hi ? u1 : u0;
      u0 = __builtin_amdgcn_ds_bpermute(src1, tw[0][1]);
      u1 = __builtin_amdgcn_ds_bpermute(src1, tw[1][1]);
      a2h.i[3] = hi ? u1 : u0;
      u0 = __builtin_amdgcn_ds_bpermute(src0, tw[0][2]);
      u1 = __builtin_amdgcn_ds_bpermute(src0, tw[1][2]);
      a2l.i[0] = hi ? u1 : u0;
      u0 = __builtin_amdgcn_ds_bpermute(src0, tw[0][3]);
      u1 = __builtin_amdgcn_ds_bpermute(src0, tw[1][3]);
      a2l.i[1] = hi ? u1 : u0;
      u0 = __builtin_amdgcn_ds_bpermute(src1, tw[0][2]);
      u1 = __builtin_amdgcn_ds_bpermute(src1, tw[1][2]);
      a2l.i[2] = hi ? u1 : u0;
      u0 = __builtin_amdgcn_ds_bpermute(src1, tw[0][3]);
      u1 = __builtin_amdgcn_ds_bpermute(src1, tw[1][3]);
      a2l.i[3] = hi ? u1 : u0;

      #pragma unroll
      for (int nt = 0; nt < 8; ++nt){
        const size_t b2base = (size_t)(nt*16 + r) * 256 + p*32 + q*8;
        bf16x8 b2h = ld_frag(w2h + b2base);
        bf16x8 b2l = ld_frag(w2l + b2base);
        acc[s][nt] = MFMA16(a2h.v, b2h, acc[s][nt], 0, 0, 0);
        acc[s][nt] = MFMA16(a2l.v, b2h, acc[s][nt], 0, 0, 0);
        acc[s][nt] = MFMA16(a2h.v, b2l, acc[s][nt], 0, 0, 0);
      }
    }
  }

  #pragma unroll
  for (int s = 0; s < 2; ++s){
    #pragma unroll
    for (int nt = 0; nt < 8; ++nt){
      #pragma unroll
      for (int i = 0; i < 4; ++i){
        const int row = rowbase + s*16 + q*4 + i;
        if (row < M){
          const size_t idx = (size_t)row * 128 + nt*16 + r;
          out[idx] += acc[s][nt][i];
        }
      }
    }
  }
}

// ---------------------------------------------------------------------------
extern "C" void kernel_launch(void* const* d_in, const int* in_sizes, int n_in,
                              void* d_out, int out_size, void* d_ws, size_t ws_size,
                              hipStream_t stream)
{
  const float* nf     = (const float*)d_in[0];
  const float* ef     = (const float*)d_in[1];
  const float* coords = (const float*)d_in[2];
  const int*   eidx   = (const int*)  d_in[3];
  const float* Wq     = (const float*)d_in[4];
  const float* Wk     = (const float*)d_in[5];
  const float* Wv     = (const float*)d_in[6];
  const float* We     = (const float*)d_in[7];
  const float* Won    = (const float*)d_in[8];
  const float* bon    = (const float*)d_in[9];
  const float* Woe    = (const float*)d_in[10];
  const float* boe    = (const float*)d_in[11];
  const float* ln1ng  = (const float*)d_in[12];
  const float* ln1nb  = (const float*)d_in[13];
  const float* ln1eg  = (const float*)d_in[14];
  const float* ln1eb  = (const float*)d_in[15];
  const float* ln2ng  = (const float*)d_in[16];
  const float* ln2nb  = (const float*)d_in[17];
  const float* ln2eg  = (const float*)d_in[18];
  const float* ln2eb  = (const float*)d_in[19];
  const float* Wn1    = (const float*)d_in[20];
  const float* Wn2    = (const float*)d_in[21];
  const float* We1    = (const float*)d_in[22];
  const float* We2    = (const float*)d_in[23];

  float* out_h = (float*)d_out;
  float* out_e = out_h + (size_t)NN * C;

  float* ws = (float*)d_ws;
  float* qb = ws;
  float* kb = qb + (size_t)NN * C;
  float* vb = kb + (size_t)NN * C;
  float* wV = vb + (size_t)NN * C;
  float* zz = wV + (size_t)NN * C;            // [NN, H]
  unsigned short* hnh = (unsigned short*)(zz + (size_t)NN * H);
  unsigned short* hnl = hnh + (size_t)NN * C;
  unsigned short* enh = hnl + (size_t)NN * C;
  unsigned short* enl = enh + (size_t)NE * C;
  unsigned short* wts = enl + (size_t)NE * C; // 8 x 32768
  unsigned short* wn1h = wts + 0*32768;
  unsigned short* wn1l = wts + 1*32768;
  unsigned short* wn2h = wts + 2*32768;
  unsigned short* wn2l = wts + 3*32768;
  unsigned short* we1h = wts + 4*32768;
  unsigned short* we1l = wts + 5*32768;
  unsigned short* we2h = wts + 6*32768;
  unsigned short* we2l = wts + 7*32768;
  unsigned short* weTh  = wts + 8*32768;
  unsigned short* weTl  = weTh + 16384;
  unsigned short* woeTh = weTl + 16384;
  unsigned short* woeTl = woeTh + 16384;
  float*          we128 = (float*)(woeTl + 16384);
  // CSR scratch (ints) after we128:
  int* ideg  = (int*)(we128 + 128);   // degree, later reused as cursor
  int* itmp  = ideg + NN;             // per-element exclusive prefix (block-local)
  int* ibsum = itmp + NN;             // block sums   [256]
  int* ibpre = ibsum + 256;           // block prefix [256]
  int* irowp = ibpre + 256;           // rowptr [NN+1]
  int* icsr  = irowp + NN + 1;        // edge ids sorted by col [NE]
  // axbuf [NE][8] fp32 aliased onto hnh/hnl (19.2MB < 25.6MB): written by
  // k_edge_mfma, consumed by k_gather, BEFORE k_node_final writes hnh/hnl.
  float* axbuf = (float*)hnh;

  hipLaunchKernelGGL(k_prep, dim3(641), dim3(256), 0, stream,
                     Wn1, Wn2, We1, We2, We, Woe,
                     wts, weTh, weTl, woeTh, woeTl, we128);
  hipLaunchKernelGGL(k_node_ln_qkv, dim3((NN + 7) / 8), dim3(256), 0, stream,
                     nf, Wq, Wk, Wv, ln1ng, ln1nb, qb, kb, vb);
  // CSR build (int arrays are tiny; L2-resident)
  hipLaunchKernelGGL(k_zero, dim3(196), dim3(256), 0, stream,
                     (float*)ideg, (size_t)NN);
  hipLaunchKernelGGL(k_count, dim3((NE + 255) / 256), dim3(256), 0, stream,
                     eidx, ideg);
  hipLaunchKernelGGL(k_scan1, dim3(NB1), dim3(256), 0, stream,
                     ideg, itmp, ibsum);
  hipLaunchKernelGGL(k_scan2, dim3(1), dim3(256), 0, stream,
                     ibsum, ibpre);
  hipLaunchKernelGGL(k_scan3, dim3(NB1), dim3(256), 0, stream,
                     itmp, ibpre, irowp, ideg);
  hipLaunchKernelGGL(k_fill, dim3((NE + 255) / 256), dim3(256), 0, stream,
                     eidx, ideg, icsr);
  // Edge pipeline (no atomics; writes ax)
  hipLaunchKernelGGL(k_edge_mfma, dim3(NE / 64), dim3(256), 0, stream,
                     ef, coords, eidx, qb, kb,
                     weTh, weTl, we128, woeTh, woeTl, boe,
                     ln1eg, ln1eb, ln2eg, ln2eb,
                     axbuf, out_e, enh, enl);
  // Node-side aggregation (replaces atomic scatter + k_zero of wV/zz)
  hipLaunchKernelGGL(k_gather, dim3((NN + 3) / 4), dim3(256), 0, stream,
                     irowp, icsr, eidx, vb, axbuf, wV, zz);
  hipLaunchKernelGGL(k_node_final, dim3(1024), dim3(256), 0, stream,
                     nf, wV, zz, Won, bon, ln2ng, ln2nb, out_h, hnh, hnl);
  hipLaunchKernelGGL(k_ffn_mfma, dim3((NN + 127) / 128), dim3(256), 0, stream,
                     NN, hnh, hnl, wn1h, wn1l, wn2h, wn2l, out_h);
  hipLaunchKernelGGL(k_ffn_mfma, dim3((NE + 127) / 128), dim3(256), 0, stream,
                     NE, enh, enl, we1h, we1l, we2h, we2l, out_e);
}

// Round 12
// 2654.030 us; speedup vs baseline: 2.5674x; 1.0439x over previous
//
#include <hip/hip_runtime.h>
#include <math.h>

#define NN 50000
#define NE 600000
#define C 128
#define H 8
#define LN_EPS 1e-5f
#define NB1 196   // ceil(NN/256)

typedef __attribute__((ext_vector_type(8))) short bf16x8;
typedef __attribute__((ext_vector_type(4))) float f32x4;
#define MFMA16 __builtin_amdgcn_mfma_f32_16x16x32_bf16

__device__ __forceinline__ float clip5(float x){ return fminf(fmaxf(x, -5.f), 5.f); }

__device__ __forceinline__ float red32(float v){
  v += __shfl_xor(v, 1);  v += __shfl_xor(v, 2);  v += __shfl_xor(v, 4);
  v += __shfl_xor(v, 8);  v += __shfl_xor(v, 16);
  return v;
}

// manual RNE float->bf16 (bits) and back
__device__ __forceinline__ unsigned short f2bf(float f){
  union { float f; unsigned u; } c; c.f = f;
  unsigned r = (c.u + 0x7fffu + ((c.u >> 16) & 1u)) >> 16;
  return (unsigned short)r;
}
__device__ __forceinline__ float bf2f(unsigned short u){
  union { unsigned u; float f; } c; c.u = ((unsigned)u) << 16;
  return c.f;
}

__device__ __forceinline__ bf16x8 ld_frag(const unsigned short* p){
  return *(const bf16x8*)p;
}

// ---------------------------------------------------------------------------
// Kernel 1: node LN1 + fused QKV projection.  8 nodes / 256-thread block.
// ---------------------------------------------------------------------------
__global__ void __launch_bounds__(256)
k_node_ln_qkv(const float* __restrict__ nf,
              const float* __restrict__ Wq, const float* __restrict__ Wk,
              const float* __restrict__ Wv,
              const float* __restrict__ g, const float* __restrict__ b,
              float* __restrict__ qb, float* __restrict__ kb, float* __restrict__ vb)
{
  __shared__ __align__(16) float s_h[8][C];
  const int tid = threadIdx.x;
  const int slot = tid >> 5, tg = tid & 31, c0 = tg * 4;
  const int node = blockIdx.x * 8 + slot;
  const bool valid = node < NN;
  const size_t nn = valid ? (size_t)node : 0;

  const float4 x = *(const float4*)(nf + nn * C + c0);
  float s  = x.x + x.y + x.z + x.w;
  float sq = x.x*x.x + x.y*x.y + x.z*x.z + x.w*x.w;
  s = red32(s); sq = red32(sq);
  const float mu   = s * (1.0f / C);
  const float rstd = rsqrtf(sq * (1.0f / C) - mu * mu + LN_EPS);
  const float4 gg = *(const float4*)(g + c0);
  const float4 bb = *(const float4*)(b + c0);
  float4 hv;
  hv.x = (x.x - mu) * rstd * gg.x + bb.x;
  hv.y = (x.y - mu) * rstd * gg.y + bb.y;
  hv.z = (x.z - mu) * rstd * gg.z + bb.z;
  hv.w = (x.w - mu) * rstd * gg.w + bb.w;
  *(float4*)&s_h[slot][c0] = hv;
  __syncthreads();

  const float4* Wq4 = (const float4*)Wq;
  const float4* Wk4 = (const float4*)Wk;
  const float4* Wv4 = (const float4*)Wv;
  float aq0=0,aq1=0,aq2=0,aq3=0, ak0=0,ak1=0,ak2=0,ak3=0, av0=0,av1=0,av2=0,av3=0;
  #pragma unroll 8
  for (int k = 0; k < C; ++k){
    const float h = s_h[slot][k];
    const float4 wq = Wq4[k*32 + tg];
    const float4 wk = Wk4[k*32 + tg];
    const float4 wv = Wv4[k*32 + tg];
    aq0 += h*wq.x; aq1 += h*wq.y; aq2 += h*wq.z; aq3 += h*wq.w;
    ak0 += h*wk.x; ak1 += h*wk.y; ak2 += h*wk.z; ak3 += h*wk.w;
    av0 += h*wv.x; av1 += h*wv.y; av2 += h*wv.z; av3 += h*wv.w;
  }
  if (valid){
    float4 o;
    o.x=aq0; o.y=aq1; o.z=aq2; o.w=aq3; *(float4*)(qb + nn*C + c0) = o;
    o.x=ak0; o.y=ak1; o.z=ak2; o.w=ak3; *(float4*)(kb + nn*C + c0) = o;
    o.x=av0; o.y=av1; o.z=av2; o.w=av3; *(float4*)(vb + nn*C + c0) = o;
  }
}

// ---------------------------------------------------------------------------
__global__ void k_zero(float* __restrict__ p, size_t n){
  size_t i = (size_t)blockIdx.x * blockDim.x + threadIdx.x;
  const size_t st = (size_t)gridDim.x * blockDim.x;
  for (; i < n; i += st) p[i] = 0.f;
}

// ---------------------------------------------------------------------------
// Prep: transposed + hi/lo-split bf16 copies of FFN weights, WeT, WoeT,
// and the dist row We[128] fp32.
// ---------------------------------------------------------------------------
__global__ void __launch_bounds__(256)
k_prep(const float* __restrict__ Wn1, const float* __restrict__ Wn2,
       const float* __restrict__ We1, const float* __restrict__ We2,
       const float* __restrict__ We,  const float* __restrict__ Woe,
       unsigned short* __restrict__ o,
       unsigned short* __restrict__ weTh, unsigned short* __restrict__ weTl,
       unsigned short* __restrict__ woeTh, unsigned short* __restrict__ woeTl,
       float* __restrict__ we128f)
{
  const int id = blockIdx.x * 256 + threadIdx.x;
  if (id < 131072){
    const int w = id >> 15, e = id & 32767;
    const float* src; int K, Nn;
    if      (w == 0){ src = Wn1; K = 128; Nn = 256; }
    else if (w == 1){ src = Wn2; K = 256; Nn = 128; }
    else if (w == 2){ src = We1; K = 128; Nn = 256; }
    else            { src = We2; K = 256; Nn = 128; }
    const int n = (K == 128) ? (e >> 7) : (e >> 8);
    const int k = e - n * K;
    const float v = src[(size_t)k * Nn + n];
    const unsigned short h = f2bf(v);
    const unsigned short l = f2bf(v - bf2f(h));
    unsigned short* oh = o + (size_t)w * 65536;
    oh[e] = h;
    oh[32768 + e] = l;
  } else if (id < 147456){
    const int e = id - 131072;
    const int n = e >> 7, k = e & 127;
    const float v = We[(size_t)k * 128 + n];
    const unsigned short h = f2bf(v);
    weTh[e] = h; weTl[e] = f2bf(v - bf2f(h));
  } else if (id < 163840){
    const int e = id - 147456;
    const int n = e >> 7, k = e & 127;
    const float v = Woe[(size_t)k * 128 + n];
    const unsigned short h = f2bf(v);
    woeTh[e] = h; woeTl[e] = f2bf(v - bf2f(h));
  } else if (id < 163968){
    const int c = id - 163840;
    we128f[c] = We[128 * 128 + c];
  }
}

// ---------------------------------------------------------------------------
// CSR build: histogram -> block scan (3 phases) -> cursor fill.
// ---------------------------------------------------------------------------
__global__ void __launch_bounds__(256)
k_count(const int* __restrict__ eidx, int* __restrict__ deg){
  const int e = blockIdx.x * 256 + threadIdx.x;
  if (e < NE) atomicAdd(&deg[eidx[NE + e]], 1);
}

__global__ void __launch_bounds__(256)
k_scan1(const int* __restrict__ deg, int* __restrict__ ex, int* __restrict__ bsum){
  __shared__ int sd[256];
  const int i = threadIdx.x;
  const int t = blockIdx.x * 256 + i;
  const int v = (t < NN) ? deg[t] : 0;
  sd[i] = v;
  __syncthreads();
  for (int off = 1; off < 256; off <<= 1){
    const int add = (i >= off) ? sd[i - off] : 0;
    __syncthreads();
    sd[i] += add;
    __syncthreads();
  }
  if (t < NN) ex[t] = sd[i] - v;            // exclusive prefix within block
  if (i == 255) bsum[blockIdx.x] = sd[255]; // block total
}

__global__ void __launch_bounds__(256)
k_scan2(const int* __restrict__ bsum, int* __restrict__ bpre){
  __shared__ int sd[256];
  const int i = threadIdx.x;
  const int v = (i < NB1) ? bsum[i] : 0;
  sd[i] = v;
  __syncthreads();
  for (int off = 1; off < 256; off <<= 1){
    const int add = (i >= off) ? sd[i - off] : 0;
    __syncthreads();
    sd[i] += add;
    __syncthreads();
  }
  if (i < NB1) bpre[i] = sd[i] - v;
}

__global__ void __launch_bounds__(256)
k_scan3(const int* __restrict__ ex, const int* __restrict__ bpre,
        int* __restrict__ rowptr, int* __restrict__ cursor){
  const int t = blockIdx.x * 256 + threadIdx.x;
  if (t < NN){
    const int r = ex[t] + bpre[t >> 8];
    rowptr[t] = r;
    cursor[t] = r;
    if (t == 0) rowptr[NN] = NE;
  }
}

__global__ void __launch_bounds__(256)
k_fill(const int* __restrict__ eidx, int* __restrict__ cursor, int* __restrict__ csr){
  const int e = blockIdx.x * 256 + threadIdx.x;
  if (e < NE){
    const int col = eidx[NE + e];
    const int pos = atomicAdd(&cursor[col], 1);
    csr[pos] = e;
  }
}

// ---------------------------------------------------------------------------
// Gather: one wave per node, lane owns 2 channels.  wV = sum(ax * v[row]),
// z = sum(ax).  Deterministic fp32 register accumulation, no atomics.
// ---------------------------------------------------------------------------
__global__ void __launch_bounds__(256)
k_gather(const int* __restrict__ rowptr, const int* __restrict__ csr,
         const int* __restrict__ eidx, const float* __restrict__ vb,
         const float* __restrict__ axbuf,
         float* __restrict__ wV, float* __restrict__ zz)
{
  const int wid = threadIdx.x >> 6, lane = threadIdx.x & 63;
  const int n = blockIdx.x * 4 + wid;
  if (n >= NN) return;
  const int s = rowptr[n], t = rowptr[n + 1];
  const int c0 = lane * 2, h = lane >> 3;   // channels c0,c0+1 belong to head h
  float a0 = 0.f, a1 = 0.f, zacc = 0.f;
  for (int p = s; p < t; ++p){
    const int eid = csr[p];
    const int row = eidx[eid];
    const float ax = axbuf[(size_t)eid * 8 + h];
    const float2 vv = *(const float2*)(vb + (size_t)row * 128 + c0);
    a0 += vv.x * ax; a1 += vv.y * ax;
    if (lane < 8) zacc += axbuf[(size_t)eid * 8 + lane];
  }
  wV[(size_t)n * 128 + c0]     = a0;
  wV[(size_t)n * 128 + c0 + 1] = a1;
  if (lane < 8) zz[(size_t)n * 8 + lane] = zacc;
}

// ---------------------------------------------------------------------------
// Kernel 3: MFMA edge pipeline (batched operand loads: all frags for a MFMA
// burst are loaded into registers BEFORE the chain -> ~2 latency exposures
// per k-window instead of ~16).  16 edges/wave, 64 edges/block, zero LDS.
// ---------------------------------------------------------------------------
__global__ void __launch_bounds__(256, 2)
k_edge_mfma(const float* __restrict__ ef, const float* __restrict__ coords,
            const int* __restrict__ eidx,
            const float* __restrict__ qb, const float* __restrict__ kb,
            const unsigned short* __restrict__ weTh, const unsigned short* __restrict__ weTl,
            const float* __restrict__ we128,
            const unsigned short* __restrict__ woeTh, const unsigned short* __restrict__ woeTl,
            const float* __restrict__ boe,
            const float* __restrict__ g1, const float* __restrict__ b1,
            const float* __restrict__ g2, const float* __restrict__ b2,
            float* __restrict__ axbuf,
            float* __restrict__ e2_out,
            unsigned short* __restrict__ enh, unsigned short* __restrict__ enl)
{
  const int tid  = threadIdx.x;
  const int wid  = tid >> 6;
  const int lane = tid & 63;
  const int r = lane & 15, q = lane >> 4;
  const int ebase = (blockIdx.x * 4 + wid) * 16;   // NE % 64 == 0: no tail
  const int edge  = ebase + r;
  const size_t e128 = (size_t)edge * 128;

  // ---- load ef slice + LN1 stats (reduce across q via shfl_xor 16,32) ----
  float xv[32];
  #pragma unroll
  for (int gk = 0; gk < 4; ++gk){
    const float4 a = *(const float4*)(ef + e128 + gk*32 + q*8);
    const float4 b = *(const float4*)(ef + e128 + gk*32 + q*8 + 4);
    xv[gk*8+0]=a.x; xv[gk*8+1]=a.y; xv[gk*8+2]=a.z; xv[gk*8+3]=a.w;
    xv[gk*8+4]=b.x; xv[gk*8+5]=b.y; xv[gk*8+6]=b.z; xv[gk*8+7]=b.w;
  }
  float s = 0.f, sq = 0.f;
  #pragma unroll
  for (int j = 0; j < 32; ++j){ s += xv[j]; sq += xv[j]*xv[j]; }
  s  += __shfl_xor(s, 16);  s  += __shfl_xor(s, 32);
  sq += __shfl_xor(sq, 16); sq += __shfl_xor(sq, 32);
  const float mu   = s * (1.f/128.f);
  const float rstd = rsqrtf(sq * (1.f/128.f) - mu*mu + LN_EPS);

  bf16x8 bhf[4], blf[4];
  #pragma unroll
  for (int gk = 0; gk < 4; ++gk){
    const float4 ga = *(const float4*)(g1 + gk*32 + q*8);
    const float4 gb = *(const float4*)(g1 + gk*32 + q*8 + 4);
    const float4 ba = *(const float4*)(b1 + gk*32 + q*8);
    const float4 bb = *(const float4*)(b1 + gk*32 + q*8 + 4);
    const float gv[8] = {ga.x,ga.y,ga.z,ga.w,gb.x,gb.y,gb.z,gb.w};
    const float bv[8] = {ba.x,ba.y,ba.z,ba.w,bb.x,bb.y,bb.z,bb.w};
    union { unsigned short u[8]; bf16x8 v; } ph, pl;
    #pragma unroll
    for (int j = 0; j < 8; ++j){
      const float e = (xv[gk*8+j] - mu) * rstd * gv[j] + bv[j];
      ph.u[j] = f2bf(e);
      pl.u[j] = f2bf(e - bf2f(ph.u[j]));
    }
    bhf[gk] = ph.v; blf[gk] = pl.v;
  }

  // ---- edge meta (lane-local: this lane's edge = ebase + r) ----
  const int row = eidx[edge];
  const int col = eidx[NE + edge];
  float dist;
  {
    const size_t r3 = (size_t)row*3, c3 = (size_t)col*3;
    const float dx = coords[r3+0]-coords[c3+0];
    const float dy = coords[r3+1]-coords[c3+1];
    const float dz = coords[r3+2]-coords[c3+2];
    dist = 0.1f * sqrtf(dx*dx + dy*dy + dz*dz);
  }

  const int src0 = (r + ((lane & 16) << 1)) << 2;
  const int src1 = src0 + 64;
  const bool hisel = (lane >= 32);

  f32x4 acc[8];
  #pragma unroll
  for (int nt = 0; nt < 8; ++nt) acc[nt] = (f32x4){0.f,0.f,0.f,0.f};

  #pragma unroll
  for (int w4 = 0; w4 < 4; ++w4){
    int tw[2][4];
    #pragma unroll
    for (int t = 0; t < 2; ++t){
      const int p = 2*w4 + t;
      // ---- batch-load all GEMM1 operands for this tile ----
      bf16x8 ah[4], al[4];
      const size_t abase = (size_t)(p*16 + r) * 128 + q*8;
      #pragma unroll
      for (int gk = 0; gk < 4; ++gk){
        ah[gk] = ld_frag(weTh + abase + gk*32);
        al[gk] = ld_frag(weTl + abase + gk*32);
      }
      const float4 w128 = *(const float4*)(we128 + p*16 + q*4);
      const float4 kr   = *(const float4*)(kb + (size_t)row*128 + p*16 + q*4);
      const float4 qc   = *(const float4*)(qb + (size_t)col*128 + p*16 + q*4);
      // ---- MFMA burst ----
      f32x4 c = (f32x4){0.f,0.f,0.f,0.f};
      #pragma unroll
      for (int gk = 0; gk < 4; ++gk){
        c = MFMA16(ah[gk], bhf[gk], c, 0, 0, 0);
        c = MFMA16(ah[gk], blf[gk], c, 0, 0, 0);
        c = MFMA16(al[gk], bhf[gk], c, 0, 0, 0);
      }
      float al4[4];
      al4[0] = clip5(kr.x*qc.x*0.25f) * (c[0] + dist*w128.x);
      al4[1] = clip5(kr.y*qc.y*0.25f) * (c[1] + dist*w128.y);
      al4[2] = clip5(kr.z*qc.z*0.25f) * (c[2] + dist*w128.z);
      al4[3] = clip5(kr.w*qc.w*0.25f) * (c[3] + dist*w128.w);

      // head-p sum (16 ch = 4 in-lane x 4 q-groups)
      float hs = al4[0]+al4[1]+al4[2]+al4[3];
      hs += __shfl_xor(hs, 16); hs += __shfl_xor(hs, 32);
      const float ax = expf(clip5(hs));

      // store per-edge attention weight (replaces atomic scatter)
      if (q == 0) axbuf[(size_t)edge * 8 + p] = ax;

      // pack alpha -> bf16 hi/lo words for bpermute
      unsigned short th[4], tl[4];
      #pragma unroll
      for (int i = 0; i < 4; ++i){
        th[i] = f2bf(al4[i]);
        tl[i] = f2bf(al4[i] - bf2f(th[i]));
      }
      tw[t][0] = (int)th[0] | ((int)th[1] << 16);
      tw[t][1] = (int)th[2] | ((int)th[3] << 16);
      tw[t][2] = (int)tl[0] | ((int)tl[1] << 16);
      tw[t][3] = (int)tl[2] | ((int)tl[3] << 16);
    }

    // redistribute alpha (D1 layout) -> A2 frag layout via quad permutation
    union { int i[4]; bf16x8 v; } a2h, a2l;
    int u0, u1;
    u0 = __builtin_amdgcn_ds_bpermute(src0, tw[0][0]);
    u1 = __builtin_amdgcn_ds_bpermute(src0, tw[1][0]);
    a2h.i[0] = hisel ? u1 : u0;
    u0 = __builtin_amdgcn_ds_bpermute(src0, tw[0][1]);
    u1 = __builtin_amdgcn_ds_bpermute(src0, tw[1][1]);
    a2h.i[1] = hisel ? u1 : u0;
    u0 = __builtin_amdgcn_ds_bpermute(src1, tw[0][0]);
    u1 = __builtin_amdgcn_ds_bpermute(src1, tw[1][0]);
    a2h.i[2] = hisel ? u1 : u0;
    u0 = __builtin_amdgcn_ds_bpermute(src1, tw[0][1]);
    u1 = __builtin_amdgcn_ds_bpermute(src1, tw[1][1]);
    a2h.i[3] = hisel ? u1 : u0;
    u0 = __builtin_amdgcn_ds_bpermute(src0, tw[0][2]);
    u1 = __builtin_amdgcn_ds_bpermute(src0, tw[1][2]);
    a2l.i[0] = hisel ? u1 : u0;
    u0 = __builtin_amdgcn_ds_bpermute(src0, tw[0][3]);
    u1 = __builtin_amdgcn_ds_bpermute(src0, tw[1][3]);
    a2l.i[1] = hisel ? u1 : u0;
    u0 = __builtin_amdgcn_ds_bpermute(src1, tw[0][2]);
    u1 = __builtin_amdgcn_ds_bpermute(src1, tw[1][2]);
    a2l.i[2] = hisel ? u1 : u0;
    u0 = __builtin_amdgcn_ds_bpermute(src1, tw[0][3]);
    u1 = __builtin_amdgcn_ds_bpermute(src1, tw[1][3]);
    a2l.i[3] = hisel ? u1 : u0;

    // GEMM2 partial, k-window w4: batch-load weights in chunks of 4 nt
    #pragma unroll
    for (int ntc = 0; ntc < 2; ++ntc){
      bf16x8 b2hF[4], b2lF[4];
      #pragma unroll
      for (int j = 0; j < 4; ++j){
        const int nt = ntc*4 + j;
        const size_t b2base = (size_t)(nt*16 + r)*128 + w4*32 + q*8;
        b2hF[j] = ld_frag(woeTh + b2base);
        b2lF[j] = ld_frag(woeTl + b2base);
      }
      #pragma unroll
      for (int j = 0; j < 4; ++j){
        const int nt = ntc*4 + j;
        acc[nt] = MFMA16(a2h.v, b2hF[j], acc[nt], 0, 0, 0);
        acc[nt] = MFMA16(a2l.v, b2hF[j], acc[nt], 0, 0, 0);
        acc[nt] = MFMA16(a2h.v, b2lF[j], acc[nt], 0, 0, 0);
      }
    }
  }

  // ---- epilogue: residual + LN2 + stores (D2: edge = ebase+q*4+i, n = nt*16+r)
  float boev[8], g2v[8], b2v[8];
  #pragma unroll
  for (int nt = 0; nt < 8; ++nt){
    boev[nt] = boe[nt*16 + r];
    g2v[nt]  = g2[nt*16 + r];
    b2v[nt]  = b2[nt*16 + r];
  }
  #pragma unroll
  for (int i = 0; i < 4; ++i){
    const int erow = ebase + q*4 + i;
    const size_t base = (size_t)erow * 128;
    float o[8];
    float s2 = 0.f, sq2 = 0.f;
    #pragma unroll
    for (int nt = 0; nt < 8; ++nt){
      o[nt] = acc[nt][i] + ef[base + nt*16 + r] + boev[nt];
      s2 += o[nt]; sq2 += o[nt]*o[nt];
    }
    s2  += __shfl_xor(s2, 1);  s2  += __shfl_xor(s2, 2);
    s2  += __shfl_xor(s2, 4);  s2  += __shfl_xor(s2, 8);
    sq2 += __shfl_xor(sq2, 1); sq2 += __shfl_xor(sq2, 2);
    sq2 += __shfl_xor(sq2, 4); sq2 += __shfl_xor(sq2, 8);
    const float mu2   = s2 * (1.f/128.f);
    const float rstd2 = rsqrtf(sq2 * (1.f/128.f) - mu2*mu2 + LN_EPS);
    #pragma unroll
    for (int nt = 0; nt < 8; ++nt){
      e2_out[base + nt*16 + r] = o[nt];
      const float en = (o[nt] - mu2)*rstd2*g2v[nt] + b2v[nt];
      const unsigned short h = f2bf(en);
      enh[base + nt*16 + r] = h;
      enl[base + nt*16 + r] = f2bf(en - bf2f(h));
    }
  }
}

// ---------------------------------------------------------------------------
// Kernel 4: node attention epilogue; emits hn as bf16 hi/lo.
// ---------------------------------------------------------------------------
__global__ void __launch_bounds__(256)
k_node_final(const float* __restrict__ nf, const float* __restrict__ wV,
             const float* __restrict__ zz,
             const float* __restrict__ Won, const float* __restrict__ bon,
             const float* __restrict__ g2, const float* __restrict__ b2,
             float* __restrict__ h2_out,
             unsigned short* __restrict__ hnh, unsigned short* __restrict__ hnl)
{
  __shared__ __align__(16) float sW[128*128];
  __shared__ __align__(16) float s_h[8][C];
  const int tid = threadIdx.x;
  {
    const float4* a = (const float4*)Won; float4* sa = (float4*)sW;
    for (int i = tid; i < 128*32; i += 256) sa[i] = a[i];
  }
  __syncthreads();
  const int slot = tid >> 5, tg = tid & 31, c0 = tg * 4;
  const float4* sW4 = (const float4*)sW;

  for (int n0 = blockIdx.x * 8; n0 < NN; n0 += gridDim.x * 8){
    const int node = n0 + slot;
    const bool valid = node < NN;
    const size_t nn = valid ? (size_t)node : 0;

    const float4 wv = *(const float4*)(wV + nn * C + c0);
    const float  zh = zz[nn * H + (c0 >> 4)] + 1e-6f;
    {
      float4 ha;
      ha.x = wv.x / zh; ha.y = wv.y / zh; ha.z = wv.z / zh; ha.w = wv.w / zh;
      *(float4*)&s_h[slot][c0] = ha;
    }
    __syncthreads();

    const float4 x  = *(const float4*)(nf + nn * C + c0);
    const float4 bo = *(const float4*)(bon + c0);
    float o0 = x.x + bo.x, o1 = x.y + bo.y, o2 = x.z + bo.z, o3 = x.w + bo.w;
    #pragma unroll 8
    for (int k = 0; k < C; ++k){
      const float hv = s_h[slot][k];
      const float4 w = sW4[k*32 + tg];
      o0 += hv*w.x; o1 += hv*w.y; o2 += hv*w.z; o3 += hv*w.w;
    }

    float s2  = o0 + o1 + o2 + o3;
    float sq2 = o0*o0 + o1*o1 + o2*o2 + o3*o3;
    s2 = red32(s2); sq2 = red32(sq2);
    const float mu2   = s2 * (1.0f / C);
    const float rstd2 = rsqrtf(sq2 * (1.0f / C) - mu2 * mu2 + LN_EPS);
    if (valid){
      float4 o; o.x=o0; o.y=o1; o.z=o2; o.w=o3;
      *(float4*)(h2_out + (size_t)node * C + c0) = o;
      const float4 gg = *(const float4*)(g2 + c0);
      const float4 bb = *(const float4*)(b2 + c0);
      float h0 = (o0 - mu2)*rstd2*gg.x + bb.x;
      float h1 = (o1 - mu2)*rstd2*gg.y + bb.y;
      float h2 = (o2 - mu2)*rstd2*gg.z + bb.z;
      float h3 = (o3 - mu2)*rstd2*gg.w + bb.w;
      ushort4 hh, ll;
      hh.x = f2bf(h0); ll.x = f2bf(h0 - bf2f(hh.x));
      hh.y = f2bf(h1); ll.y = f2bf(h1 - bf2f(hh.y));
      hh.z = f2bf(h2); ll.z = f2bf(h2 - bf2f(hh.z));
      hh.w = f2bf(h3); ll.w = f2bf(h3 - bf2f(hh.w));
      *(ushort4*)(hnh + (size_t)node * C + c0) = hh;
      *(ushort4*)(hnl + (size_t)node * C + c0) = ll;
    }
    __syncthreads();
  }
}

// ---------------------------------------------------------------------------
// Kernel 5: MFMA FFN with batched operand loads (same math/order as round 2;
// loads hoisted into register batches before each MFMA burst).
// ---------------------------------------------------------------------------
__global__ void __launch_bounds__(256, 2)
k_ffn_mfma(int M,
           const unsigned short* __restrict__ xh, const unsigned short* __restrict__ xl,
           const unsigned short* __restrict__ w1h, const unsigned short* __restrict__ w1l,
           const unsigned short* __restrict__ w2h, const unsigned short* __restrict__ w2l,
           float* __restrict__ out)
{
  const int tid  = threadIdx.x;
  const int wid  = tid >> 6;
  const int lane = tid & 63;
  const int r = lane & 15;
  const int q = lane >> 4;
  const int rowbase = (blockIdx.x * 4 + wid) * 32;

  bf16x8 bh[2][4], bl[2][4];
  #pragma unroll
  for (int s = 0; s < 2; ++s){
    int row = rowbase + s*16 + r;
    if (row > M-1) row = M-1;
    const size_t base = (size_t)row * 128 + q * 8;
    #pragma unroll
    for (int gk = 0; gk < 4; ++gk){
      bh[s][gk] = ld_frag(xh + base + gk*32);
      bl[s][gk] = ld_frag(xl + base + gk*32);
    }
  }

  f32x4 acc[2][8];
  #pragma unroll
  for (int s = 0; s < 2; ++s)
    #pragma unroll
    for (int nt = 0; nt < 8; ++nt)
      acc[s][nt] = (f32x4){0.f, 0.f, 0.f, 0.f};

  const int src0 = (r + ((lane & 16) << 1)) << 2;
  const int src1 = src0 + 64;
  const bool hi = (lane >= 32);

  for (int p = 0; p < 8; ++p){
    int tw[2][2][4];                 // [s][t][w]
    #pragma unroll
    for (int t = 0; t < 2; ++t){
      // ---- batch-load GEMM1 weight frags for this tile (shared by both s) --
      bf16x8 ah[4], al[4];
      const size_t abase = (size_t)((2*p + t)*16 + r) * 128 + q*8;
      #pragma unroll
      for (int gk = 0; gk < 4; ++gk){
        ah[gk] = ld_frag(w1h + abase + gk*32);
        al[gk] = ld_frag(w1l + abase + gk*32);
      }
      // ---- MFMA burst: two independent accumulator chains (s=0,1) ----
      f32x4 c[2];
      c[0] = (f32x4){0.f,0.f,0.f,0.f};
      c[1] = (f32x4){0.f,0.f,0.f,0.f};
      #pragma unroll
      for (int gk = 0; gk < 4; ++gk){
        c[0] = MFMA16(ah[gk], bh[0][gk], c[0], 0, 0, 0);
        c[1] = MFMA16(ah[gk], bh[1][gk], c[1], 0, 0, 0);
        c[0] = MFMA16(ah[gk], bl[0][gk], c[0], 0, 0, 0);
        c[1] = MFMA16(ah[gk], bl[1][gk], c[1], 0, 0, 0);
        c[0] = MFMA16(al[gk], bh[0][gk], c[0], 0, 0, 0);
        c[1] = MFMA16(al[gk], bh[1][gk], c[1], 0, 0, 0);
      }
      #pragma unroll
      for (int s = 0; s < 2; ++s){
        unsigned short th[4], tl_[4];
        #pragma unroll
        for (int i = 0; i < 4; ++i){
          float v = c[s][i];
          v = v / (1.f + __expf(-v));     // silu
          th[i]  = f2bf(v);
          tl_[i] = f2bf(v - bf2f(th[i]));
        }
        tw[s][t][0] = (int)th[0]  | ((int)th[1]  << 16);
        tw[s][t][1] = (int)th[2]  | ((int)th[3]  << 16);
        tw[s][t][2] = (int)tl_[0] | ((int)tl_[1] << 16);
        tw[s][t][3] = (int)tl_[2] | ((int)tl_[3] << 16);
      }
    }

    // ---- redistribute t -> A2 frags per s ----
    union { int i[4]; bf16x8 v; } a2h[2], a2l[2];
    #pragma unroll
    for (int s = 0; s < 2; ++s){
      int u0, u1;
      u0 = __builtin_amdgcn_ds_bpermute(src0, tw[s][0][0]);
      u1 = __builtin_amdgcn_ds_bpermute(src0, tw[s][1][0]);
      a2h[s].i[0] = hi ? u1 : u0;
      u0 = __builtin_amdgcn_ds_bpermute(src0, tw[s][0][1]);
      u1 = __builtin_amdgcn_ds_bpermute(src0, tw[s][1][1]);
      a2h[s].i[1] = hi ? u1 : u0;
      u0 = __builtin_amdgcn_ds_bpermute(src1, tw[s][0][0]);
      u1 = __builtin_amdgcn_ds_bpermute(src1, tw[s][1][0]);
      a2h[s].i[2] = hi ? u1 : u0;
      u0 = __builtin_amdgcn_ds_bpermute(src1, tw[s][0][1]);
      u1 = __builtin_amdgcn_ds_bpermute(src1, tw[s][1][1]);
      a2h[s].i[3] = hi ? u1 : u0;
      u0 = __builtin_amdgcn_ds_bpermute(src0, tw[s][0][2]);
      u1 = __builtin_amdgcn_ds_bpermute(src0, tw[s][1][2]);
      a2l[s].i[0] = hi ? u1 : u0;
      u0 = __builtin_amdgcn_ds_bpermute(src0, tw[s][0][3]);
      u1 = __builtin_amdgcn_ds_bpermute(src0, tw[s][1][3]);
      a2l[s].i[1] = hi ? u1 : u0;
      u0 = __builtin_amdgcn_ds_bpermute(src1, tw[s][0][2]);
      u1 = __builtin_amdgcn_ds_bpermute(src1, tw[s][1][2]);
      a2l[s].i[2] = hi ? u1 : u0;
      u0 = __builtin_amdgcn_ds_bpermute(src1, tw[s][0][3]);
      u1 = __builtin_amdgcn_ds_bpermute(src1, tw[s][1][3]);
      a2l[s].i[3] = hi ? u1 : u0;
    }

    // ---- GEMM2: batch-load weights in chunks of 4 nt, then MFMA burst ----
    #pragma unroll
    for (int ntc = 0; ntc < 2; ++ntc){
      bf16x8 b2hF[4], b2lF[4];
      #pragma unroll
      for (int j = 0; j < 4; ++j){
        const int nt = ntc*4 + j;
        const size_t b2base = (size_t)(nt*16 + r) * 256 + p*32 + q*8;
        b2hF[j] = ld_frag(w2h + b2base);
        b2lF[j] = ld_frag(w2l + b2base);
      }
      #pragma unroll
      for (int j = 0; j < 4; ++j){
        const int nt = ntc*4 + j;
        #pragma unroll
        for (int s = 0; s < 2; ++s){
          acc[s][nt] = MFMA16(a2h[s].v, b2hF[j], acc[s][nt], 0, 0, 0);
          acc[s][nt] = MFMA16(a2l[s].v, b2hF[j], acc[s][nt], 0, 0, 0);
          acc[s][nt] = MFMA16(a2h[s].v, b2lF[j], acc[s][nt], 0, 0, 0);
        }
      }
    }
  }

  #pragma unroll
  for (int s = 0; s < 2; ++s){
    #pragma unroll
    for (int nt = 0; nt < 8; ++nt){
      #pragma unroll
      for (int i = 0; i < 4; ++i){
        const int row = rowbase + s*16 + q*4 + i;
        if (row < M){
          const size_t idx = (size_t)row * 128 + nt*16 + r;
          out[idx] += acc[s][nt][i];
        }
      }
    }
  }
}

// ---------------------------------------------------------------------------
extern "C" void kernel_launch(void* const* d_in, const int* in_sizes, int n_in,
                              void* d_out, int out_size, void* d_ws, size_t ws_size,
                              hipStream_t stream)
{
  const float* nf     = (const float*)d_in[0];
  const float* ef     = (const float*)d_in[1];
  const float* coords = (const float*)d_in[2];
  const int*   eidx   = (const int*)  d_in[3];
  const float* Wq     = (const float*)d_in[4];
  const float* Wk     = (const float*)d_in[5];
  const float* Wv     = (const float*)d_in[6];
  const float* We     = (const float*)d_in[7];
  const float* Won    = (const float*)d_in[8];
  const float* bon    = (const float*)d_in[9];
  const float* Woe    = (const float*)d_in[10];
  const float* boe    = (const float*)d_in[11];
  const float* ln1ng  = (const float*)d_in[12];
  const float* ln1nb  = (const float*)d_in[13];
  const float* ln1eg  = (const float*)d_in[14];
  const float* ln1eb  = (const float*)d_in[15];
  const float* ln2ng  = (const float*)d_in[16];
  const float* ln2nb  = (const float*)d_in[17];
  const float* ln2eg  = (const float*)d_in[18];
  const float* ln2eb  = (const float*)d_in[19];
  const float* Wn1    = (const float*)d_in[20];
  const float* Wn2    = (const float*)d_in[21];
  const float* We1    = (const float*)d_in[22];
  const float* We2    = (const float*)d_in[23];

  float* out_h = (float*)d_out;
  float* out_e = out_h + (size_t)NN * C;

  float* ws = (float*)d_ws;
  float* qb = ws;
  float* kb = qb + (size_t)NN * C;
  float* vb = kb + (size_t)NN * C;
  float* wV = vb + (size_t)NN * C;
  float* zz = wV + (size_t)NN * C;            // [NN, H]
  unsigned short* hnh = (unsigned short*)(zz + (size_t)NN * H);
  unsigned short* hnl = hnh + (size_t)NN * C;
  unsigned short* enh = hnl + (size_t)NN * C;
  unsigned short* enl = enh + (size_t)NE * C;
  unsigned short* wts = enl + (size_t)NE * C; // 8 x 32768
  unsigned short* wn1h = wts + 0*32768;
  unsigned short* wn1l = wts + 1*32768;
  unsigned short* wn2h = wts + 2*32768;
  unsigned short* wn2l = wts + 3*32768;
  unsigned short* we1h = wts + 4*32768;
  unsigned short* we1l = wts + 5*32768;
  unsigned short* we2h = wts + 6*32768;
  unsigned short* we2l = wts + 7*32768;
  unsigned short* weTh  = wts + 8*32768;
  unsigned short* weTl  = weTh + 16384;
  unsigned short* woeTh = weTl + 16384;
  unsigned short* woeTl = woeTh + 16384;
  float*          we128 = (float*)(woeTl + 16384);
  // CSR scratch (ints) after we128:
  int* ideg  = (int*)(we128 + 128);   // degree, later reused as cursor
  int* itmp  = ideg + NN;             // per-element exclusive prefix (block-local)
  int* ibsum = itmp + NN;             // block sums   [256]
  int* ibpre = ibsum + 256;           // block prefix [256]
  int* irowp = ibpre + 256;           // rowptr [NN+1]
  int* icsr  = irowp + NN + 1;        // edge ids sorted by col [NE]
  // axbuf [NE][8] fp32 aliased onto hnh/hnl (19.2MB < 25.6MB): written by
  // k_edge_mfma, consumed by k_gather, BEFORE k_node_final writes hnh/hnl.
  float* axbuf = (float*)hnh;

  hipLaunchKernelGGL(k_prep, dim3(641), dim3(256), 0, stream,
                     Wn1, Wn2, We1, We2, We, Woe,
                     wts, weTh, weTl, woeTh, woeTl, we128);
  hipLaunchKernelGGL(k_node_ln_qkv, dim3((NN + 7) / 8), dim3(256), 0, stream,
                     nf, Wq, Wk, Wv, ln1ng, ln1nb, qb, kb, vb);
  // CSR build (int arrays are tiny; L2-resident)
  hipLaunchKernelGGL(k_zero, dim3(196), dim3(256), 0, stream,
                     (float*)ideg, (size_t)NN);
  hipLaunchKernelGGL(k_count, dim3((NE + 255) / 256), dim3(256), 0, stream,
                     eidx, ideg);
  hipLaunchKernelGGL(k_scan1, dim3(NB1), dim3(256), 0, stream,
                     ideg, itmp, ibsum);
  hipLaunchKernelGGL(k_scan2, dim3(1), dim3(256), 0, stream,
                     ibsum, ibpre);
  hipLaunchKernelGGL(k_scan3, dim3(NB1), dim3(256), 0, stream,
                     itmp, ibpre, irowp, ideg);
  hipLaunchKernelGGL(k_fill, dim3((NE + 255) / 256), dim3(256), 0, stream,
                     eidx, ideg, icsr);
  // Edge pipeline (no atomics; writes ax)
  hipLaunchKernelGGL(k_edge_mfma, dim3(NE / 64), dim3(256), 0, stream,
                     ef, coords, eidx, qb, kb,
                     weTh, weTl, we128, woeTh, woeTl, boe,
                     ln1eg, ln1eb, ln2eg, ln2eb,
                     axbuf, out_e, enh, enl);
  // Node-side aggregation (replaces atomic scatter + k_zero of wV/zz)
  hipLaunchKernelGGL(k_gather, dim3((NN + 3) / 4), dim3(256), 0, stream,
                     irowp, icsr, eidx, vb, axbuf, wV, zz);
  hipLaunchKernelGGL(k_node_final, dim3(1024), dim3(256), 0, stream,
                     nf, wV, zz, Won, bon, ln2ng, ln2nb, out_h, hnh, hnl);
  hipLaunchKernelGGL(k_ffn_mfma, dim3((NN + 127) / 128), dim3(256), 0, stream,
                     NN, hnh, hnl, wn1h, wn1l, wn2h, wn2l, out_h);
  hipLaunchKernelGGL(k_ffn_mfma, dim3((NE + 127) / 128), dim3(256), 0, stream,
                     NE, enh, enl, we1h, we1l, we2h, we2l, out_e);
}